// Round 7
// baseline (173.568 us; speedup 1.0000x reference)
//
#include <hip/hip_runtime.h>

// Problem constants
#define BB 256   // batch
#define HH 512   // hidden
#define CC 64    // spline channels
#define NN 100   // time knots
#define KT 8     // K_TERMS

typedef short s16x8 __attribute__((ext_vector_type(8)));
typedef float f32x4 __attribute__((ext_vector_type(4)));

#define MFMA16(a, b, c) __builtin_amdgcn_mfma_f32_16x16x32_bf16((a), (b), (c), 0, 0, 0)

static __device__ __forceinline__ unsigned short f2bf(float f) {
    union { float f; unsigned int u; } v; v.f = f;
    unsigned int r = v.u + 0x7FFFu + ((v.u >> 16) & 1u);  // RNE
    return (unsigned short)(r >> 16);
}

// ---------------------------------------------------------------------------
// A-frag layout for a 16-row x 512-col bf16 activation tile t (8192 halfwords):
//   F[t*8192 + g*512 + lane*8 + e] = M[lane&15][g*32 + (lane>>4)*8 + e]
// K-half s (cols [s*256,(s+1)*256)) = halfwords [s*4096,(s+1)*4096): contiguous.
// ---------------------------------------------------------------------------

// ---------------------------------------------------------------------------
// k_pack: weight bf16 conversion into MFMA-frag-packed layout + h conversion +
// cubic spline evaluation (x, xdot).  (Round-1 proven version.)
// ---------------------------------------------------------------------------
__global__ void k_pack(const float* __restrict__ wh, const float* __restrict__ wout,
                       const float* __restrict__ wx, const float* __restrict__ h,
                       const float* __restrict__ coeffs, const float* __restrict__ dcoeffs,
                       const float* __restrict__ tobs, const float* __restrict__ tg,
                       unsigned short* __restrict__ whp, unsigned short* __restrict__ wop,
                       unsigned short* __restrict__ wxp, unsigned short* __restrict__ hb,
                       unsigned short* __restrict__ xb, unsigned short* __restrict__ xdb) {
    int gid = blockIdx.x * 256 + threadIdx.x;
    if (gid < 524288) {                       // wh / wout packed (262144 each)
        const float* src = (gid < 262144) ? wh : wout;
        unsigned short* dst = (gid < 262144) ? whp : wop;
        int p = gid & 262143;
        int e = p & 7, lane = (p >> 3) & 63, g = (p >> 9) & 15, cg = (p >> 13) & 1, w = p >> 14;
        int row = w * 32 + cg * 16 + (lane & 15);
        int k = g * 32 + (lane >> 4) * 8 + e;
        dst[p] = f2bf(src[row * HH + k]);
    } else if (gid < 557056) {                // wx packed (32768)
        int p = gid - 524288;
        int e = p & 7, lane = (p >> 3) & 63, g = (p >> 9) & 1, cg = (p >> 10) & 1, w = p >> 11;
        int row = w * 32 + cg * 16 + (lane & 15);
        int k = g * 32 + (lane >> 4) * 8 + e;
        wxp[p] = f2bf(wx[row * CC + k]);
    } else if (gid < 688128) {                // h -> bf16 row-major (131072)
        int p = gid - 557056;
        hb[p] = f2bf(h[p]);
    } else if (gid < 704512) {                // spline eval: x, xdot (16384)
        int p = gid - 688128;
        int b = p >> 6, c = p & 63;
        float t = tg[0];
        int cntv = 0;
        for (int n = 0; n < NN; n++) cntv += (tobs[n] <= t) ? 1 : 0;
        int idx = cntv - 1;
        idx = idx < 0 ? 0 : (idx > NN - 2 ? NN - 2 : idx);  // clip to [0, 98]
        float dt = t - tobs[idx];
        const float* cb = coeffs + ((size_t)(b * (NN - 1) + idx) * 4) * CC + c;
        float xv = cb[0] + dt * (cb[CC] + dt * (cb[2 * CC] + dt * cb[3 * CC]));
        const float* db = dcoeffs + ((size_t)(b * (NN - 1) + idx) * 4) * CC + c;
        float xd = db[0] + dt * (db[CC] + dt * (db[2 * CC] + dt * db[3 * CC]));
        xb[p] = f2bf(xv);
        xdb[p] = f2bf(xd);
    }
}

// ---------------------------------------------------------------------------
// k_l1: l1 = x@wx^T + h@wh^T + b0 -> relu(bf16), drelu=sigmoid(l1) (f32)
//       fused: v = xdot@wx^T ; s0 = drelu*v (bf16)          (round-1 proven)
// ---------------------------------------------------------------------------
__global__ void k_l1(const unsigned short* __restrict__ whp, const unsigned short* __restrict__ wxp,
                     const unsigned short* __restrict__ hb, const unsigned short* __restrict__ xb,
                     const unsigned short* __restrict__ xdb, const float* __restrict__ b0g,
                     unsigned short* __restrict__ relu_b, float* __restrict__ drelu_f,
                     unsigned short* __restrict__ s0_b) {
    __shared__ unsigned short sh[32][520];
    __shared__ unsigned short sx[32][72];
    __shared__ unsigned short sxd[32][72];
    int tid = threadIdx.x;
    int b0 = blockIdx.x * 32;
    int it = blockIdx.y;
    for (int idx = tid; idx < 32 * 64; idx += 256) {
        int r = idx >> 6, c8 = idx & 63;
        *(int4*)&sh[r][c8 * 8] = *(const int4*)&hb[(b0 + r) * HH + c8 * 8];
    }
    for (int idx = tid; idx < 32 * 8; idx += 256) {
        int r = idx >> 3, c8 = idx & 7;
        *(int4*)&sx[r][c8 * 8] = *(const int4*)&xb[(b0 + r) * CC + c8 * 8];
        *(int4*)&sxd[r][c8 * 8] = *(const int4*)&xdb[(b0 + r) * CC + c8 * 8];
    }
    __syncthreads();
    int wv = tid >> 6, lane = tid & 63, col = lane & 15, kq = lane >> 4;
    int isub = it * 64 + wv * 16;
    int wpk = isub >> 5, cg = (isub >> 4) & 1;
    f32x4 acc0 = {0.f, 0.f, 0.f, 0.f}, acc1 = {0.f, 0.f, 0.f, 0.f};
    f32x4 vac0 = {0.f, 0.f, 0.f, 0.f}, vac1 = {0.f, 0.f, 0.f, 0.f};
    const s16x8* whfrag = (const s16x8*)whp + (size_t)((wpk * 2 + cg) * 16) * 64 + lane;
#pragma unroll
    for (int g = 0; g < 16; g++) {
        s16x8 bf = whfrag[g * 64];
        s16x8 a0 = *(const s16x8*)&sh[col][g * 32 + kq * 8];
        s16x8 a1 = *(const s16x8*)&sh[16 + col][g * 32 + kq * 8];
        acc0 = MFMA16(a0, bf, acc0);
        acc1 = MFMA16(a1, bf, acc1);
    }
    const s16x8* wxfrag = (const s16x8*)wxp + (size_t)((wpk * 2 + cg) * 2) * 64 + lane;
#pragma unroll
    for (int g = 0; g < 2; g++) {
        s16x8 bf = wxfrag[g * 64];
        s16x8 a0 = *(const s16x8*)&sx[col][g * 32 + kq * 8];
        s16x8 a1 = *(const s16x8*)&sx[16 + col][g * 32 + kq * 8];
        acc0 = MFMA16(a0, bf, acc0);
        acc1 = MFMA16(a1, bf, acc1);
        s16x8 d0 = *(const s16x8*)&sxd[col][g * 32 + kq * 8];
        s16x8 d1 = *(const s16x8*)&sxd[16 + col][g * 32 + kq * 8];
        vac0 = MFMA16(d0, bf, vac0);
        vac1 = MFMA16(d1, bf, vac1);
    }
    int ic = isub + col;
    float bias = b0g[ic];
#pragma unroll
    for (int r = 0; r < 4; r++) {
        int bb = b0 + kq * 4 + r;
        float l1a = acc0[r] + bias;
        float dra = 1.f / (1.f + expf(-l1a));
        relu_b[bb * HH + ic] = f2bf(fmaxf(l1a, 0.f));
        drelu_f[bb * HH + ic] = dra;
        s0_b[bb * HH + ic] = f2bf(dra * vac0[r]);
        float l1b = acc1[r] + bias;
        float drb = 1.f / (1.f + expf(-l1b));
        relu_b[(bb + 16) * HH + ic] = f2bf(fmaxf(l1b, 0.f));
        drelu_f[(bb + 16) * HH + ic] = drb;
        s0_b[(bb + 16) * HH + ic] = f2bf(drb * vac1[r]);
    }
}

// ---------------------------------------------------------------------------
// k_th: z = relu@wout^T + b1 -> th=tanh(z), dtanh=1-th^2 (f32)
//       fused: curr0 = dtanh * (s0@wout^T); stores curr0 f32 row-major and
//       bf16 A-frag. Also zeroes the loop kernel's sync flags (block 0,0).
// ---------------------------------------------------------------------------
__global__ void k_th(const unsigned short* __restrict__ wop, const unsigned short* __restrict__ relu_b,
                     const unsigned short* __restrict__ s0_b, const float* __restrict__ b1g,
                     float* __restrict__ dtanh_f, unsigned short* __restrict__ curr_b,
                     float* __restrict__ curr0_f, unsigned int* __restrict__ flg) {
    __shared__ unsigned short sr[32][520];
    __shared__ unsigned short ss0[32][520];
    int tid = threadIdx.x;
    if (blockIdx.x == 0 && blockIdx.y == 0) {  // zero 512 flag words (32 flags, 64B stride)
        flg[tid] = 0u;
        flg[tid + 256] = 0u;
    }
    int b0 = blockIdx.x * 32;
    int it = blockIdx.y;
    for (int idx = tid; idx < 32 * 64; idx += 256) {
        int r = idx >> 6, c8 = idx & 63;
        *(int4*)&sr[r][c8 * 8] = *(const int4*)&relu_b[(b0 + r) * HH + c8 * 8];
        *(int4*)&ss0[r][c8 * 8] = *(const int4*)&s0_b[(b0 + r) * HH + c8 * 8];
    }
    __syncthreads();
    int wv = tid >> 6, lane = tid & 63, col = lane & 15, kq = lane >> 4;
    int isub = it * 64 + wv * 16;
    int wpk = isub >> 5, cg = (isub >> 4) & 1;
    f32x4 acc0 = {0.f, 0.f, 0.f, 0.f}, acc1 = {0.f, 0.f, 0.f, 0.f};
    f32x4 cac0 = {0.f, 0.f, 0.f, 0.f}, cac1 = {0.f, 0.f, 0.f, 0.f};
    const s16x8* wofrag = (const s16x8*)wop + (size_t)((wpk * 2 + cg) * 16) * 64 + lane;
#pragma unroll
    for (int g = 0; g < 16; g++) {
        s16x8 bf = wofrag[g * 64];
        s16x8 a0 = *(const s16x8*)&sr[col][g * 32 + kq * 8];
        s16x8 a1 = *(const s16x8*)&sr[16 + col][g * 32 + kq * 8];
        acc0 = MFMA16(a0, bf, acc0);
        acc1 = MFMA16(a1, bf, acc1);
        s16x8 p0 = *(const s16x8*)&ss0[col][g * 32 + kq * 8];
        s16x8 p1 = *(const s16x8*)&ss0[16 + col][g * 32 + kq * 8];
        cac0 = MFMA16(p0, bf, cac0);
        cac1 = MFMA16(p1, bf, cac1);
    }
    int ic = isub + col;
    float bias = b1g[ic];
    int fc = (ic >> 5) * 512 + (ic & 7) + (((ic >> 3) & 3) << 7);
#pragma unroll
    for (int r = 0; r < 4; r++) {
        int bb = b0 + kq * 4 + r;
        int row8 = (kq * 4 + r) * 8;
        float th_a = tanhf(acc0[r] + bias);
        float dta = 1.f - th_a * th_a;
        float c0a = dta * cac0[r];
        dtanh_f[bb * HH + ic] = dta;
        curr_b[(bb >> 4) * 8192 + fc + row8] = f2bf(c0a);
        curr0_f[bb * HH + ic] = c0a;
        float th_b = tanhf(acc1[r] + bias);
        float dtb = 1.f - th_b * th_b;
        float c0b = dtb * cac1[r];
        dtanh_f[(bb + 16) * HH + ic] = dtb;
        curr_b[((bb + 16) >> 4) * 8192 + fc + row8] = f2bf(c0b);
        curr0_f[(bb + 16) * HH + ic] = c0b;
    }
}

// ---------------------------------------------------------------------------
// k_loop7: 2-way split Neumann loop (round-6 protocol) with the exchange
// moved to MID-PHASE so it hides under own-half compute.
// Per phase: [part 1] GEMM over MY K-half (groups s*8..s*8+7 — my half of
// curr is in LDS the moment my previous epilogue's barrier completed, no
// waiting) -> [exchange] spin (partner's flag was posted a half-phase ago,
// so this is usually immediate) + stage partner 8KB -> [part 2] GEMM over
// partner K-half. K-order for s=1 blocks becomes a rotation by 8 groups
// (fp32 accumulation reorder only). Export/flag protocol, slots, and race
// proof identical to round 6. No ternary pointer selection in unrolled
// loops (round-4 spill lesson): the j=7 boundary step is explicit.
// ---------------------------------------------------------------------------
__global__ __launch_bounds__(512) void k_loop7(
    const unsigned short* __restrict__ whp, const unsigned short* __restrict__ wop,
    const unsigned short* __restrict__ curr_b, const float* __restrict__ curr0_f,
    const float* __restrict__ drelu_f, const float* __restrict__ dtanh_f,
    unsigned short* __restrict__ xch, unsigned int* flg,
    float* __restrict__ outp) {
    __shared__ __align__(16) unsigned short sa[2][8192];  // ping-pong A-frag (16KB each)
    const int tid = threadIdx.x;
    const int w = tid >> 6, lane = tid & 63;
    const int col2 = lane & 15, kq = lane >> 4;
    const int c = blockIdx.x & 15;   // chain (batch tile)
    const int s = blockIdx.x >> 4;   // column half

    // stage curr0 full tile (A-frag from k_th) into sa[0]: 1024 int4
    {
        const int4* src = (const int4*)(curr_b + (size_t)c * 8192);
        int4* dst = (int4*)&sa[0][0];
        dst[tid] = src[tid];
        dst[tid + 512] = src[tid + 512];
    }

    // per-thread diagonals + h_dot accumulator: 2 col-tiles x 4 rows (my half)
    float dr[2][4], dt[2][4], hd[2][4];
#pragma unroll
    for (int t = 0; t < 2; t++) {
        const int cc = s * 256 + (w * 2 + t) * 16 + col2;
#pragma unroll
        for (int r = 0; r < 4; r++) {
            const int row = c * 16 + kq * 4 + r;
            dr[t][r] = drelu_f[row * HH + cc];
            dt[t][r] = dtanh_f[row * HH + cc];
            hd[t][r] = curr0_f[row * HH + cc];
        }
    }

    // LDS halfword index (r=0) within my half for (row m=kq*4+r, local tile ct=w*2+t)
    int fbl[2];
#pragma unroll
    for (int t = 0; t < 2; t++)
        fbl[t] = w * 512 + (col2 & 7) + (((t * 2 + (col2 >> 3)) & 3) << 7) + kq * 32;
    const int myhalf = s * 4096;         // halfword offset of my K-half in an A-frag tile
    const int phalf = (1 - s) * 4096;

    // wave's B-frag base within my half: absolute col tiles s*16 + w*2 + t.
    // Within a phase: w1 = own-K-half groups (g=s*8+j), w2 = partner-K-half.
    const s16x8* wlh = (const s16x8*)whp + (size_t)(s * 16 + w * 2) * 1024 + lane;
    const s16x8* wlo = (const s16x8*)wop + (size_t)(s * 16 + w * 2) * 1024 + lane;
    const unsigned short* A0 = &sa[0][lane * 8];
    const unsigned short* A1 = &sa[1][lane * 8];
    unsigned int* fme = flg + (s * 16 + c) * 16;         // own 64B line
    unsigned int* fpr = flg + ((1 - s) * 16 + c) * 16;
    const int sK = s << 9;               // s16x8 offset of K-group s*8 in a col-tile (s*8*64)
    const int pK = (1 - s) << 9;

    __syncthreads();  // curr0 staged

    for (int p = 0; p < 16; p++) {
        const s16x8* wl = (p & 1) ? wlo : wlh;          // even: wh, odd: wout
        const unsigned short* Ar = (p & 1) ? A1 : A0;   // read sa[p&1]
        const s16x8* w1 = wl + sK;                      // own-half K groups
        const s16x8* w2 = wl + pK;                      // partner-half K groups
        f32x4 acc[2] = {{0.f, 0.f, 0.f, 0.f}, {0.f, 0.f, 0.f, 0.f}};
        s16x8 bfr[2][2];
#pragma unroll
        for (int t = 0; t < 2; t++) bfr[0][t] = w1[t * 1024];
        // ---- part 1: own K-half (data already in LDS; no waiting) ----
#pragma unroll
        for (int j = 0; j < 7; j++) {
#pragma unroll
            for (int t = 0; t < 2; t++) bfr[(j + 1) & 1][t] = w1[t * 1024 + (j + 1) * 64];
            const s16x8 a = *(const s16x8*)(Ar + myhalf + j * 512);
#pragma unroll
            for (int t = 0; t < 2; t++) acc[t] = MFMA16(a, bfr[j & 1][t], acc[t]);
        }
        {   // j = 7: prefetch part-2 group 0 into bfr[0]
#pragma unroll
            for (int t = 0; t < 2; t++) bfr[0][t] = w2[t * 1024];
            const s16x8 a = *(const s16x8*)(Ar + myhalf + 7 * 512);
#pragma unroll
            for (int t = 0; t < 2; t++) acc[t] = MFMA16(a, bfr[1][t], acc[t]);
        }
        // ---- mid-phase exchange: partner posted its flag a half-phase ago ----
        if (p) {
            if (tid == 0) {
                while (__hip_atomic_load(fpr, __ATOMIC_RELAXED, __HIP_MEMORY_SCOPE_AGENT)
                       < (unsigned)p) { __builtin_amdgcn_s_sleep(1); }
            }
            __syncthreads();  // flag observed
            const unsigned long long* gsrc = (const unsigned long long*)
                (xch + ((size_t)(c * 2 + ((p - 1) & 1)) * 2 + (1 - s)) * 4096);
            unsigned long long v0 = __hip_atomic_load(&gsrc[tid], __ATOMIC_RELAXED, __HIP_MEMORY_SCOPE_AGENT);
            unsigned long long v1 = __hip_atomic_load(&gsrc[tid + 512], __ATOMIC_RELAXED, __HIP_MEMORY_SCOPE_AGENT);
            unsigned long long* ld = (unsigned long long*)&sa[p & 1][phalf];
            ld[tid] = v0;
            ld[tid + 512] = v1;
            __syncthreads();  // partner half staged
        }
        // ---- part 2: partner K-half ----
#pragma unroll
        for (int j = 0; j < 7; j++) {
#pragma unroll
            for (int t = 0; t < 2; t++) bfr[(j + 1) & 1][t] = w2[t * 1024 + (j + 1) * 64];
            const s16x8 a = *(const s16x8*)(Ar + phalf + j * 512);
#pragma unroll
            for (int t = 0; t < 2; t++) acc[t] = MFMA16(a, bfr[j & 1][t], acc[t]);
        }
        {   // j = 7: no prefetch
            const s16x8 a = *(const s16x8*)(Ar + phalf + 7 * 512);
#pragma unroll
            for (int t = 0; t < 2; t++) acc[t] = MFMA16(a, bfr[1][t], acc[t]);
        }
        // ---- epilogue + export (round-6 protocol) ----
        unsigned short* Aw = &sa[(p + 1) & 1][0];       // write the other buffer
        if (p & 1) {            // wout phase: curr' = dtanh*(s@wout^T); h_dot += curr'
            if (p < 15) {
#pragma unroll
                for (int t = 0; t < 2; t++)
#pragma unroll
                    for (int r = 0; r < 4; r++) {
                        float v = dt[t][r] * acc[t][r];
                        hd[t][r] += v;
                        Aw[myhalf + fbl[t] + r * 8] = f2bf(v);
                    }
            } else {
#pragma unroll
                for (int t = 0; t < 2; t++)
#pragma unroll
                    for (int r = 0; r < 4; r++) hd[t][r] += dt[t][r] * acc[t][r];
            }
        } else {                // wh phase: s = drelu*(curr@wh^T)
#pragma unroll
            for (int t = 0; t < 2; t++)
#pragma unroll
                for (int r = 0; r < 4; r++)
                    Aw[myhalf + fbl[t] + r * 8] = f2bf(dr[t][r] * acc[t][r]);
        }
        if (p < 15) {
            __syncthreads();    // my-half LDS writes visible block-wide
            unsigned long long* gdst = (unsigned long long*)
                (xch + ((size_t)(c * 2 + (p & 1)) * 2 + s) * 4096);
            const unsigned long long* lsrc = (const unsigned long long*)&sa[(p + 1) & 1][myhalf];
            __hip_atomic_store(&gdst[tid], lsrc[tid], __ATOMIC_RELAXED, __HIP_MEMORY_SCOPE_AGENT);
            __hip_atomic_store(&gdst[tid + 512], lsrc[tid + 512], __ATOMIC_RELAXED, __HIP_MEMORY_SCOPE_AGENT);
            __syncthreads();    // all waves' exports drained (vmcnt(0) at barrier)
            if (tid == 0)
                __hip_atomic_store(fme, (unsigned)(p + 1), __ATOMIC_RELEASE, __HIP_MEMORY_SCOPE_AGENT);
        }
    }

#pragma unroll
    for (int t = 0; t < 2; t++) {
        const int cc = s * 256 + (w * 2 + t) * 16 + col2;
#pragma unroll
        for (int r = 0; r < 4; r++)
            outp[(size_t)(c * 16 + kq * 4 + r) * HH + cc] = hd[t][r];
    }
}

// ---------------------------------------------------------------------------
extern "C" void kernel_launch(void* const* d_in, const int* in_sizes, int n_in,
                              void* d_out, int out_size, void* d_ws, size_t ws_size,
                              hipStream_t stream) {
    const float* tg = (const float*)d_in[0];
    const float* h = (const float*)d_in[1];
    const float* coeffs = (const float*)d_in[2];
    const float* dcoeffs = (const float*)d_in[3];
    const float* tobs = (const float*)d_in[4];
    const float* wx = (const float*)d_in[5];
    const float* wh = (const float*)d_in[6];
    const float* wout = (const float*)d_in[7];
    const float* b0g = (const float*)d_in[8];
    const float* b1g = (const float*)d_in[9];
    float* outp = (float*)d_out;

    char* ws = (char*)d_ws;
    unsigned short* whp    = (unsigned short*)(ws + 0);        // 512KB packed bf16
    unsigned short* wop    = (unsigned short*)(ws + 524288);   // 512KB
    unsigned short* wxp    = (unsigned short*)(ws + 1048576);  // 64KB
    unsigned short* hb     = (unsigned short*)(ws + 1114112);  // 256KB
    unsigned short* xb     = (unsigned short*)(ws + 1376256);  // 32KB
    unsigned short* xdb    = (unsigned short*)(ws + 1409024);  // 32KB
    unsigned short* relu_b = (unsigned short*)(ws + 1441792);  // 256KB (dead after k_th)
    unsigned short* s0_b   = (unsigned short*)(ws + 1703936);  // 256KB (dead after k_th)
    float* drelu_f         = (float*)(ws + 1966080);           // 512KB
    float* dtanh_f         = (float*)(ws + 2490368);           // 512KB
    unsigned short* curr_b = (unsigned short*)(ws + 3014656);  // 256KB (A-frag)
    float* curr0_f         = (float*)(ws + 3276800);           // 512KB
    unsigned short* xch    = (unsigned short*)(ws + 1441792);  // 512KB exchange (overlays relu/s0)
    unsigned int* flg      = (unsigned int*)(ws + 3801088);    // 2KB flags

    k_pack<<<2752, 256, 0, stream>>>(wh, wout, wx, h, coeffs, dcoeffs, tobs, tg,
                                     whp, wop, wxp, hb, xb, xdb);
    k_l1<<<dim3(8, 8), 256, 0, stream>>>(whp, wxp, hb, xb, xdb, b0g, relu_b, drelu_f, s0_b);
    k_th<<<dim3(8, 8), 256, 0, stream>>>(wop, relu_b, s0_b, b1g, dtanh_f, curr_b, curr0_f, flg);
    k_loop7<<<32, 512, 0, stream>>>(whp, wop, curr_b, curr0_f, drelu_f, dtanh_f, xch, flg, outp);
}

// Round 8
// 171.774 us; speedup vs baseline: 1.0104x; 1.0104x over previous
//
#include <hip/hip_runtime.h>

// Problem constants
#define BB 256   // batch
#define HH 512   // hidden
#define CC 64    // spline channels
#define NN 100   // time knots
#define KT 8     // K_TERMS

typedef short s16x8 __attribute__((ext_vector_type(8)));
typedef float f32x4 __attribute__((ext_vector_type(4)));

#define MFMA16(a, b, c) __builtin_amdgcn_mfma_f32_16x16x32_bf16((a), (b), (c), 0, 0, 0)

static __device__ __forceinline__ unsigned short f2bf(float f) {
    union { float f; unsigned int u; } v; v.f = f;
    unsigned int r = v.u + 0x7FFFu + ((v.u >> 16) & 1u);  // RNE
    return (unsigned short)(r >> 16);
}

// ---------------------------------------------------------------------------
// A-frag layout for a 16-row x 512-col bf16 activation tile t (8192 halfwords):
//   F[t*8192 + g*512 + lane*8 + e] = M[lane&15][g*32 + (lane>>4)*8 + e]
// K-half s (cols [s*256,(s+1)*256)) = halfwords [s*4096,(s+1)*4096): contiguous.
// ---------------------------------------------------------------------------

// ---------------------------------------------------------------------------
// k_pack: weight bf16 conversion into MFMA-frag-packed layout + h conversion +
// cubic spline evaluation (x, xdot).  (Round-1 proven version.)
// ---------------------------------------------------------------------------
__global__ void k_pack(const float* __restrict__ wh, const float* __restrict__ wout,
                       const float* __restrict__ wx, const float* __restrict__ h,
                       const float* __restrict__ coeffs, const float* __restrict__ dcoeffs,
                       const float* __restrict__ tobs, const float* __restrict__ tg,
                       unsigned short* __restrict__ whp, unsigned short* __restrict__ wop,
                       unsigned short* __restrict__ wxp, unsigned short* __restrict__ hb,
                       unsigned short* __restrict__ xb, unsigned short* __restrict__ xdb) {
    int gid = blockIdx.x * 256 + threadIdx.x;
    if (gid < 524288) {                       // wh / wout packed (262144 each)
        const float* src = (gid < 262144) ? wh : wout;
        unsigned short* dst = (gid < 262144) ? whp : wop;
        int p = gid & 262143;
        int e = p & 7, lane = (p >> 3) & 63, g = (p >> 9) & 15, cg = (p >> 13) & 1, w = p >> 14;
        int row = w * 32 + cg * 16 + (lane & 15);
        int k = g * 32 + (lane >> 4) * 8 + e;
        dst[p] = f2bf(src[row * HH + k]);
    } else if (gid < 557056) {                // wx packed (32768)
        int p = gid - 524288;
        int e = p & 7, lane = (p >> 3) & 63, g = (p >> 9) & 1, cg = (p >> 10) & 1, w = p >> 11;
        int row = w * 32 + cg * 16 + (lane & 15);
        int k = g * 32 + (lane >> 4) * 8 + e;
        wxp[p] = f2bf(wx[row * CC + k]);
    } else if (gid < 688128) {                // h -> bf16 row-major (131072)
        int p = gid - 557056;
        hb[p] = f2bf(h[p]);
    } else if (gid < 704512) {                // spline eval: x, xdot (16384)
        int p = gid - 688128;
        int b = p >> 6, c = p & 63;
        float t = tg[0];
        int cntv = 0;
        for (int n = 0; n < NN; n++) cntv += (tobs[n] <= t) ? 1 : 0;
        int idx = cntv - 1;
        idx = idx < 0 ? 0 : (idx > NN - 2 ? NN - 2 : idx);  // clip to [0, 98]
        float dt = t - tobs[idx];
        const float* cb = coeffs + ((size_t)(b * (NN - 1) + idx) * 4) * CC + c;
        float xv = cb[0] + dt * (cb[CC] + dt * (cb[2 * CC] + dt * cb[3 * CC]));
        const float* db = dcoeffs + ((size_t)(b * (NN - 1) + idx) * 4) * CC + c;
        float xd = db[0] + dt * (db[CC] + dt * (db[2 * CC] + dt * db[3 * CC]));
        xb[p] = f2bf(xv);
        xdb[p] = f2bf(xd);
    }
}

// ---------------------------------------------------------------------------
// k_l1: l1 = x@wx^T + h@wh^T + b0 -> relu(bf16), drelu=sigmoid(l1) (f32)
//       fused: v = xdot@wx^T ; s0 = drelu*v (bf16)          (round-1 proven)
// ---------------------------------------------------------------------------
__global__ void k_l1(const unsigned short* __restrict__ whp, const unsigned short* __restrict__ wxp,
                     const unsigned short* __restrict__ hb, const unsigned short* __restrict__ xb,
                     const unsigned short* __restrict__ xdb, const float* __restrict__ b0g,
                     unsigned short* __restrict__ relu_b, float* __restrict__ drelu_f,
                     unsigned short* __restrict__ s0_b) {
    __shared__ unsigned short sh[32][520];
    __shared__ unsigned short sx[32][72];
    __shared__ unsigned short sxd[32][72];
    int tid = threadIdx.x;
    int b0 = blockIdx.x * 32;
    int it = blockIdx.y;
    for (int idx = tid; idx < 32 * 64; idx += 256) {
        int r = idx >> 6, c8 = idx & 63;
        *(int4*)&sh[r][c8 * 8] = *(const int4*)&hb[(b0 + r) * HH + c8 * 8];
    }
    for (int idx = tid; idx < 32 * 8; idx += 256) {
        int r = idx >> 3, c8 = idx & 7;
        *(int4*)&sx[r][c8 * 8] = *(const int4*)&xb[(b0 + r) * CC + c8 * 8];
        *(int4*)&sxd[r][c8 * 8] = *(const int4*)&xdb[(b0 + r) * CC + c8 * 8];
    }
    __syncthreads();
    int wv = tid >> 6, lane = tid & 63, col = lane & 15, kq = lane >> 4;
    int isub = it * 64 + wv * 16;
    int wpk = isub >> 5, cg = (isub >> 4) & 1;
    f32x4 acc0 = {0.f, 0.f, 0.f, 0.f}, acc1 = {0.f, 0.f, 0.f, 0.f};
    f32x4 vac0 = {0.f, 0.f, 0.f, 0.f}, vac1 = {0.f, 0.f, 0.f, 0.f};
    const s16x8* whfrag = (const s16x8*)whp + (size_t)((wpk * 2 + cg) * 16) * 64 + lane;
#pragma unroll
    for (int g = 0; g < 16; g++) {
        s16x8 bf = whfrag[g * 64];
        s16x8 a0 = *(const s16x8*)&sh[col][g * 32 + kq * 8];
        s16x8 a1 = *(const s16x8*)&sh[16 + col][g * 32 + kq * 8];
        acc0 = MFMA16(a0, bf, acc0);
        acc1 = MFMA16(a1, bf, acc1);
    }
    const s16x8* wxfrag = (const s16x8*)wxp + (size_t)((wpk * 2 + cg) * 2) * 64 + lane;
#pragma unroll
    for (int g = 0; g < 2; g++) {
        s16x8 bf = wxfrag[g * 64];
        s16x8 a0 = *(const s16x8*)&sx[col][g * 32 + kq * 8];
        s16x8 a1 = *(const s16x8*)&sx[16 + col][g * 32 + kq * 8];
        acc0 = MFMA16(a0, bf, acc0);
        acc1 = MFMA16(a1, bf, acc1);
        s16x8 d0 = *(const s16x8*)&sxd[col][g * 32 + kq * 8];
        s16x8 d1 = *(const s16x8*)&sxd[16 + col][g * 32 + kq * 8];
        vac0 = MFMA16(d0, bf, vac0);
        vac1 = MFMA16(d1, bf, vac1);
    }
    int ic = isub + col;
    float bias = b0g[ic];
#pragma unroll
    for (int r = 0; r < 4; r++) {
        int bb = b0 + kq * 4 + r;
        float l1a = acc0[r] + bias;
        float dra = 1.f / (1.f + expf(-l1a));
        relu_b[bb * HH + ic] = f2bf(fmaxf(l1a, 0.f));
        drelu_f[bb * HH + ic] = dra;
        s0_b[bb * HH + ic] = f2bf(dra * vac0[r]);
        float l1b = acc1[r] + bias;
        float drb = 1.f / (1.f + expf(-l1b));
        relu_b[(bb + 16) * HH + ic] = f2bf(fmaxf(l1b, 0.f));
        drelu_f[(bb + 16) * HH + ic] = drb;
        s0_b[(bb + 16) * HH + ic] = f2bf(drb * vac1[r]);
    }
}

// ---------------------------------------------------------------------------
// k_th: z = relu@wout^T + b1 -> th=tanh(z), dtanh=1-th^2 (f32)
//       fused: curr0 = dtanh * (s0@wout^T); stores curr0 f32 row-major and
//       bf16 A-frag. Also zeroes the loop kernel's sync flags (block 0,0).
// ---------------------------------------------------------------------------
__global__ void k_th(const unsigned short* __restrict__ wop, const unsigned short* __restrict__ relu_b,
                     const unsigned short* __restrict__ s0_b, const float* __restrict__ b1g,
                     float* __restrict__ dtanh_f, unsigned short* __restrict__ curr_b,
                     float* __restrict__ curr0_f, unsigned int* __restrict__ flg) {
    __shared__ unsigned short sr[32][520];
    __shared__ unsigned short ss0[32][520];
    int tid = threadIdx.x;
    if (blockIdx.x == 0 && blockIdx.y == 0) {  // zero 512 flag words (32 flags, 64B stride)
        flg[tid] = 0u;
        flg[tid + 256] = 0u;
    }
    int b0 = blockIdx.x * 32;
    int it = blockIdx.y;
    for (int idx = tid; idx < 32 * 64; idx += 256) {
        int r = idx >> 6, c8 = idx & 63;
        *(int4*)&sr[r][c8 * 8] = *(const int4*)&relu_b[(b0 + r) * HH + c8 * 8];
        *(int4*)&ss0[r][c8 * 8] = *(const int4*)&s0_b[(b0 + r) * HH + c8 * 8];
    }
    __syncthreads();
    int wv = tid >> 6, lane = tid & 63, col = lane & 15, kq = lane >> 4;
    int isub = it * 64 + wv * 16;
    int wpk = isub >> 5, cg = (isub >> 4) & 1;
    f32x4 acc0 = {0.f, 0.f, 0.f, 0.f}, acc1 = {0.f, 0.f, 0.f, 0.f};
    f32x4 cac0 = {0.f, 0.f, 0.f, 0.f}, cac1 = {0.f, 0.f, 0.f, 0.f};
    const s16x8* wofrag = (const s16x8*)wop + (size_t)((wpk * 2 + cg) * 16) * 64 + lane;
#pragma unroll
    for (int g = 0; g < 16; g++) {
        s16x8 bf = wofrag[g * 64];
        s16x8 a0 = *(const s16x8*)&sr[col][g * 32 + kq * 8];
        s16x8 a1 = *(const s16x8*)&sr[16 + col][g * 32 + kq * 8];
        acc0 = MFMA16(a0, bf, acc0);
        acc1 = MFMA16(a1, bf, acc1);
        s16x8 p0 = *(const s16x8*)&ss0[col][g * 32 + kq * 8];
        s16x8 p1 = *(const s16x8*)&ss0[16 + col][g * 32 + kq * 8];
        cac0 = MFMA16(p0, bf, cac0);
        cac1 = MFMA16(p1, bf, cac1);
    }
    int ic = isub + col;
    float bias = b1g[ic];
    int fc = (ic >> 5) * 512 + (ic & 7) + (((ic >> 3) & 3) << 7);
#pragma unroll
    for (int r = 0; r < 4; r++) {
        int bb = b0 + kq * 4 + r;
        int row8 = (kq * 4 + r) * 8;
        float th_a = tanhf(acc0[r] + bias);
        float dta = 1.f - th_a * th_a;
        float c0a = dta * cac0[r];
        dtanh_f[bb * HH + ic] = dta;
        curr_b[(bb >> 4) * 8192 + fc + row8] = f2bf(c0a);
        curr0_f[bb * HH + ic] = c0a;
        float th_b = tanhf(acc1[r] + bias);
        float dtb = 1.f - th_b * th_b;
        float c0b = dtb * cac1[r];
        dtanh_f[(bb + 16) * HH + ic] = dtb;
        curr_b[((bb + 16) >> 4) * 8192 + fc + row8] = f2bf(c0b);
        curr0_f[(bb + 16) * HH + ic] = c0b;
    }
}

// ---------------------------------------------------------------------------
// k_loop8: 2-way split Neumann loop, exchange fully pipelined.
// Changes vs k_loop7 (null at 61.5us; exchange mechanics were the cost):
//  - Exchange slot layout is THREAD-MAJOR: thread i's 8 bf16 epilogue values
//    packed into 2 u64 at slot64[i], slot64[i+512]. Producer packs in the
//    epilogue and issues 2 coalesced sc1 atomic stores from REGISTERS (no
//    LDS round-trip, no separate export step, one barrier removed).
//  - Consumer: ALL threads spin (no tid0+barrier observe step), then issue
//    the 2 sc1 u64 loads into registers and run part-1 (own K-half, ~2.3us)
//    -> L3 RTT hides under compute (T14). After part-1: unpack via 8
//    ds_write_b16 using own fbl (same tid -> same positions as producer),
//    one barrier, part-2.
//  - 2 barriers/phase (was 4); zero serial memory round-trips.
// Visibility protocol (sc1 atomics both sides + RELEASE flag) and the
// slot/flag race proof are identical to rounds 6/7.
// ---------------------------------------------------------------------------
__global__ __launch_bounds__(512) void k_loop8(
    const unsigned short* __restrict__ whp, const unsigned short* __restrict__ wop,
    const unsigned short* __restrict__ curr_b, const float* __restrict__ curr0_f,
    const float* __restrict__ drelu_f, const float* __restrict__ dtanh_f,
    unsigned short* __restrict__ xch, unsigned int* flg,
    float* __restrict__ outp) {
    __shared__ __align__(16) unsigned short sa[2][8192];  // ping-pong A-frag (16KB each)
    const int tid = threadIdx.x;
    const int w = tid >> 6, lane = tid & 63;
    const int col2 = lane & 15, kq = lane >> 4;
    const int c = blockIdx.x & 15;   // chain (batch tile)
    const int s = blockIdx.x >> 4;   // column half

    // stage curr0 full tile (A-frag from k_th) into sa[0]: 1024 int4
    {
        const int4* src = (const int4*)(curr_b + (size_t)c * 8192);
        int4* dst = (int4*)&sa[0][0];
        dst[tid] = src[tid];
        dst[tid + 512] = src[tid + 512];
    }

    // per-thread diagonals + h_dot accumulator: 2 col-tiles x 4 rows (my half)
    float dr[2][4], dt[2][4], hd[2][4];
#pragma unroll
    for (int t = 0; t < 2; t++) {
        const int cc = s * 256 + (w * 2 + t) * 16 + col2;
#pragma unroll
        for (int r = 0; r < 4; r++) {
            const int row = c * 16 + kq * 4 + r;
            dr[t][r] = drelu_f[row * HH + cc];
            dt[t][r] = dtanh_f[row * HH + cc];
            hd[t][r] = curr0_f[row * HH + cc];
        }
    }

    // LDS halfword index (r=0) within a half for (row m=kq*4+r, local tile ct=w*2+t)
    int fbl[2];
#pragma unroll
    for (int t = 0; t < 2; t++)
        fbl[t] = w * 512 + (col2 & 7) + (((t * 2 + (col2 >> 3)) & 3) << 7) + kq * 32;
    const int myhalf = s * 4096;         // halfword offset of my K-half in an A-frag tile
    const int phalf = (1 - s) * 4096;

    // wave's B-frag base within my col-half: absolute col tiles s*16 + w*2 + t.
    const s16x8* wlh = (const s16x8*)whp + (size_t)(s * 16 + w * 2) * 1024 + lane;
    const s16x8* wlo = (const s16x8*)wop + (size_t)(s * 16 + w * 2) * 1024 + lane;
    const unsigned short* A0 = &sa[0][lane * 8];
    const unsigned short* A1 = &sa[1][lane * 8];
    unsigned int* fme = flg + (s * 16 + c) * 16;         // own 64B line
    unsigned int* fpr = flg + ((1 - s) * 16 + c) * 16;
    const int sK = s << 9;               // s16x8 offset of K-group s*8 in a col-tile
    const int pK = (1 - s) << 9;

    __syncthreads();  // curr0 staged

    for (int p = 0; p < 16; p++) {
        const s16x8* wl = (p & 1) ? wlo : wlh;          // even: wh, odd: wout
        const unsigned short* Ar = (p & 1) ? A1 : A0;   // read sa[p&1]
        const s16x8* w1 = wl + sK;                      // own-half K groups
        const s16x8* w2 = wl + pK;                      // partner-half K groups

        // ---- issue-early exchange-in: spin (steady state: immediate), then
        //      load partner's packed half into registers; consume after part 1.
        unsigned long long v0 = 0ull, v1 = 0ull;
        if (p) {
            while (__hip_atomic_load(fpr, __ATOMIC_RELAXED, __HIP_MEMORY_SCOPE_AGENT)
                   < (unsigned)p) { __builtin_amdgcn_s_sleep(1); }
            const unsigned long long* gsrc = (const unsigned long long*)
                (xch + ((size_t)(c * 2 + ((p - 1) & 1)) * 2 + (1 - s)) * 4096);
            v0 = __hip_atomic_load(&gsrc[tid], __ATOMIC_RELAXED, __HIP_MEMORY_SCOPE_AGENT);
            v1 = __hip_atomic_load(&gsrc[tid + 512], __ATOMIC_RELAXED, __HIP_MEMORY_SCOPE_AGENT);
        }

        f32x4 acc[2] = {{0.f, 0.f, 0.f, 0.f}, {0.f, 0.f, 0.f, 0.f}};
        s16x8 bfr[2][2];
#pragma unroll
        for (int t = 0; t < 2; t++) bfr[0][t] = w1[t * 1024];
        // ---- part 1: own K-half (data already in LDS; hides the loads above) ----
#pragma unroll
        for (int j = 0; j < 7; j++) {
#pragma unroll
            for (int t = 0; t < 2; t++) bfr[(j + 1) & 1][t] = w1[t * 1024 + (j + 1) * 64];
            const s16x8 a = *(const s16x8*)(Ar + myhalf + j * 512);
#pragma unroll
            for (int t = 0; t < 2; t++) acc[t] = MFMA16(a, bfr[j & 1][t], acc[t]);
        }
        {   // j = 7: prefetch part-2 group 0 into bfr[0]
#pragma unroll
            for (int t = 0; t < 2; t++) bfr[0][t] = w2[t * 1024];
            const s16x8 a = *(const s16x8*)(Ar + myhalf + 7 * 512);
#pragma unroll
            for (int t = 0; t < 2; t++) acc[t] = MFMA16(a, bfr[1][t], acc[t]);
        }
        // ---- unpack staged partner half into LDS (loads completed during part 1) ----
        if (p) {
            unsigned short* ph = &sa[p & 1][phalf];
#pragma unroll
            for (int r = 0; r < 4; r++) {
                ph[fbl[0] + r * 8] = (unsigned short)(v0 >> (16 * r));
                ph[fbl[1] + r * 8] = (unsigned short)(v1 >> (16 * r));
            }
        }
        __syncthreads();  // partner half visible to all waves
        // ---- part 2: partner K-half ----
#pragma unroll
        for (int j = 0; j < 7; j++) {
#pragma unroll
            for (int t = 0; t < 2; t++) bfr[(j + 1) & 1][t] = w2[t * 1024 + (j + 1) * 64];
            const s16x8 a = *(const s16x8*)(Ar + phalf + j * 512);
#pragma unroll
            for (int t = 0; t < 2; t++) acc[t] = MFMA16(a, bfr[j & 1][t], acc[t]);
        }
        {   // j = 7: no prefetch
            const s16x8 a = *(const s16x8*)(Ar + phalf + 7 * 512);
#pragma unroll
            for (int t = 0; t < 2; t++) acc[t] = MFMA16(a, bfr[1][t], acc[t]);
        }
        // ---- epilogue: LDS own-half write + register-sourced packed export ----
        unsigned short* Aw = &sa[(p + 1) & 1][0];
        if (p < 15) {
            unsigned long long pk0 = 0ull, pk1 = 0ull;
            if (p & 1) {        // wout phase: curr' = dtanh*(s@wout^T); h_dot += curr'
#pragma unroll
                for (int r = 0; r < 4; r++) {
                    float va = dt[0][r] * acc[0][r];
                    hd[0][r] += va;
                    unsigned short ba = f2bf(va);
                    Aw[myhalf + fbl[0] + r * 8] = ba;
                    pk0 |= (unsigned long long)ba << (16 * r);
                    float vb = dt[1][r] * acc[1][r];
                    hd[1][r] += vb;
                    unsigned short bb = f2bf(vb);
                    Aw[myhalf + fbl[1] + r * 8] = bb;
                    pk1 |= (unsigned long long)bb << (16 * r);
                }
            } else {            // wh phase: s = drelu*(curr@wh^T)
#pragma unroll
                for (int r = 0; r < 4; r++) {
                    unsigned short ba = f2bf(dr[0][r] * acc[0][r]);
                    Aw[myhalf + fbl[0] + r * 8] = ba;
                    pk0 |= (unsigned long long)ba << (16 * r);
                    unsigned short bb = f2bf(dr[1][r] * acc[1][r]);
                    Aw[myhalf + fbl[1] + r * 8] = bb;
                    pk1 |= (unsigned long long)bb << (16 * r);
                }
            }
            unsigned long long* gdst = (unsigned long long*)
                (xch + ((size_t)(c * 2 + (p & 1)) * 2 + s) * 4096);
            __hip_atomic_store(&gdst[tid], pk0, __ATOMIC_RELAXED, __HIP_MEMORY_SCOPE_AGENT);
            __hip_atomic_store(&gdst[tid + 512], pk1, __ATOMIC_RELAXED, __HIP_MEMORY_SCOPE_AGENT);
            __syncthreads();    // drains LDS writes AND the export stores (vmcnt(0))
            if (tid == 0)
                __hip_atomic_store(fme, (unsigned)(p + 1), __ATOMIC_RELEASE, __HIP_MEMORY_SCOPE_AGENT);
        } else {                // p == 15 (wout): accumulate only
#pragma unroll
            for (int t = 0; t < 2; t++)
#pragma unroll
                for (int r = 0; r < 4; r++) hd[t][r] += dt[t][r] * acc[t][r];
        }
    }

#pragma unroll
    for (int t = 0; t < 2; t++) {
        const int cc = s * 256 + (w * 2 + t) * 16 + col2;
#pragma unroll
        for (int r = 0; r < 4; r++)
            outp[(size_t)(c * 16 + kq * 4 + r) * HH + cc] = hd[t][r];
    }
}

// ---------------------------------------------------------------------------
extern "C" void kernel_launch(void* const* d_in, const int* in_sizes, int n_in,
                              void* d_out, int out_size, void* d_ws, size_t ws_size,
                              hipStream_t stream) {
    const float* tg = (const float*)d_in[0];
    const float* h = (const float*)d_in[1];
    const float* coeffs = (const float*)d_in[2];
    const float* dcoeffs = (const float*)d_in[3];
    const float* tobs = (const float*)d_in[4];
    const float* wx = (const float*)d_in[5];
    const float* wh = (const float*)d_in[6];
    const float* wout = (const float*)d_in[7];
    const float* b0g = (const float*)d_in[8];
    const float* b1g = (const float*)d_in[9];
    float* outp = (float*)d_out;

    char* ws = (char*)d_ws;
    unsigned short* whp    = (unsigned short*)(ws + 0);        // 512KB packed bf16
    unsigned short* wop    = (unsigned short*)(ws + 524288);   // 512KB
    unsigned short* wxp    = (unsigned short*)(ws + 1048576);  // 64KB
    unsigned short* hb     = (unsigned short*)(ws + 1114112);  // 256KB
    unsigned short* xb     = (unsigned short*)(ws + 1376256);  // 32KB
    unsigned short* xdb    = (unsigned short*)(ws + 1409024);  // 32KB
    unsigned short* relu_b = (unsigned short*)(ws + 1441792);  // 256KB (dead after k_th)
    unsigned short* s0_b   = (unsigned short*)(ws + 1703936);  // 256KB (dead after k_th)
    float* drelu_f         = (float*)(ws + 1966080);           // 512KB
    float* dtanh_f         = (float*)(ws + 2490368);           // 512KB
    unsigned short* curr_b = (unsigned short*)(ws + 3014656);  // 256KB (A-frag)
    float* curr0_f         = (float*)(ws + 3276800);           // 512KB
    unsigned short* xch    = (unsigned short*)(ws + 1441792);  // 512KB exchange (overlays relu/s0)
    unsigned int* flg      = (unsigned int*)(ws + 3801088);    // 2KB flags

    k_pack<<<2752, 256, 0, stream>>>(wh, wout, wx, h, coeffs, dcoeffs, tobs, tg,
                                     whp, wop, wxp, hb, xb, xdb);
    k_l1<<<dim3(8, 8), 256, 0, stream>>>(whp, wxp, hb, xb, xdb, b0g, relu_b, drelu_f, s0_b);
    k_th<<<dim3(8, 8), 256, 0, stream>>>(wop, relu_b, s0_b, b1g, dtanh_f, curr_b, curr0_f, flg);
    k_loop8<<<32, 512, 0, stream>>>(whp, wop, curr_b, curr0_f, drelu_f, dtanh_f, xch, flg, outp);
}

// Round 9
// 164.558 us; speedup vs baseline: 1.0548x; 1.0439x over previous
//
#include <hip/hip_runtime.h>

// Problem constants
#define BB 256   // batch
#define HH 512   // hidden
#define CC 64    // spline channels
#define NN 100   // time knots
#define KT 8     // K_TERMS

typedef short s16x8 __attribute__((ext_vector_type(8)));
typedef float f32x4 __attribute__((ext_vector_type(4)));

#define MFMA16(a, b, c) __builtin_amdgcn_mfma_f32_16x16x32_bf16((a), (b), (c), 0, 0, 0)

static __device__ __forceinline__ unsigned short f2bf(float f) {
    union { float f; unsigned int u; } v; v.f = f;
    unsigned int r = v.u + 0x7FFFu + ((v.u >> 16) & 1u);  // RNE
    return (unsigned short)(r >> 16);
}

// ---------------------------------------------------------------------------
// A-frag layout for a 16-row x 512-col bf16 activation tile t (8192 halfwords):
//   F[t*8192 + g*512 + lane*8 + e] = M[lane&15][g*32 + (lane>>4)*8 + e]
// K-half s (cols [s*256,(s+1)*256)) = halfwords [s*4096,(s+1)*4096): contiguous.
// ---------------------------------------------------------------------------

// ---------------------------------------------------------------------------
// k_pack: weight bf16 conversion into MFMA-frag-packed layout + h conversion +
// cubic spline evaluation (x, xdot).  (Round-1 proven version.)
// ---------------------------------------------------------------------------
__global__ void k_pack(const float* __restrict__ wh, const float* __restrict__ wout,
                       const float* __restrict__ wx, const float* __restrict__ h,
                       const float* __restrict__ coeffs, const float* __restrict__ dcoeffs,
                       const float* __restrict__ tobs, const float* __restrict__ tg,
                       unsigned short* __restrict__ whp, unsigned short* __restrict__ wop,
                       unsigned short* __restrict__ wxp, unsigned short* __restrict__ hb,
                       unsigned short* __restrict__ xb, unsigned short* __restrict__ xdb) {
    int gid = blockIdx.x * 256 + threadIdx.x;
    if (gid < 524288) {                       // wh / wout packed (262144 each)
        const float* src = (gid < 262144) ? wh : wout;
        unsigned short* dst = (gid < 262144) ? whp : wop;
        int p = gid & 262143;
        int e = p & 7, lane = (p >> 3) & 63, g = (p >> 9) & 15, cg = (p >> 13) & 1, w = p >> 14;
        int row = w * 32 + cg * 16 + (lane & 15);
        int k = g * 32 + (lane >> 4) * 8 + e;
        dst[p] = f2bf(src[row * HH + k]);
    } else if (gid < 557056) {                // wx packed (32768)
        int p = gid - 524288;
        int e = p & 7, lane = (p >> 3) & 63, g = (p >> 9) & 1, cg = (p >> 10) & 1, w = p >> 11;
        int row = w * 32 + cg * 16 + (lane & 15);
        int k = g * 32 + (lane >> 4) * 8 + e;
        wxp[p] = f2bf(wx[row * CC + k]);
    } else if (gid < 688128) {                // h -> bf16 row-major (131072)
        int p = gid - 557056;
        hb[p] = f2bf(h[p]);
    } else if (gid < 704512) {                // spline eval: x, xdot (16384)
        int p = gid - 688128;
        int b = p >> 6, c = p & 63;
        float t = tg[0];
        int cntv = 0;
        for (int n = 0; n < NN; n++) cntv += (tobs[n] <= t) ? 1 : 0;
        int idx = cntv - 1;
        idx = idx < 0 ? 0 : (idx > NN - 2 ? NN - 2 : idx);  // clip to [0, 98]
        float dt = t - tobs[idx];
        const float* cb = coeffs + ((size_t)(b * (NN - 1) + idx) * 4) * CC + c;
        float xv = cb[0] + dt * (cb[CC] + dt * (cb[2 * CC] + dt * cb[3 * CC]));
        const float* db = dcoeffs + ((size_t)(b * (NN - 1) + idx) * 4) * CC + c;
        float xd = db[0] + dt * (db[CC] + dt * (db[2 * CC] + dt * db[3 * CC]));
        xb[p] = f2bf(xv);
        xdb[p] = f2bf(xd);
    }
}

// ---------------------------------------------------------------------------
// k_l1: l1 = x@wx^T + h@wh^T + b0 -> relu(bf16), drelu=sigmoid(l1) (f32)
//       fused: v = xdot@wx^T ; s0 = drelu*v (bf16)          (round-1 proven)
// ---------------------------------------------------------------------------
__global__ void k_l1(const unsigned short* __restrict__ whp, const unsigned short* __restrict__ wxp,
                     const unsigned short* __restrict__ hb, const unsigned short* __restrict__ xb,
                     const unsigned short* __restrict__ xdb, const float* __restrict__ b0g,
                     unsigned short* __restrict__ relu_b, float* __restrict__ drelu_f,
                     unsigned short* __restrict__ s0_b) {
    __shared__ unsigned short sh[32][520];
    __shared__ unsigned short sx[32][72];
    __shared__ unsigned short sxd[32][72];
    int tid = threadIdx.x;
    int b0 = blockIdx.x * 32;
    int it = blockIdx.y;
    for (int idx = tid; idx < 32 * 64; idx += 256) {
        int r = idx >> 6, c8 = idx & 63;
        *(int4*)&sh[r][c8 * 8] = *(const int4*)&hb[(b0 + r) * HH + c8 * 8];
    }
    for (int idx = tid; idx < 32 * 8; idx += 256) {
        int r = idx >> 3, c8 = idx & 7;
        *(int4*)&sx[r][c8 * 8] = *(const int4*)&xb[(b0 + r) * CC + c8 * 8];
        *(int4*)&sxd[r][c8 * 8] = *(const int4*)&xdb[(b0 + r) * CC + c8 * 8];
    }
    __syncthreads();
    int wv = tid >> 6, lane = tid & 63, col = lane & 15, kq = lane >> 4;
    int isub = it * 64 + wv * 16;
    int wpk = isub >> 5, cg = (isub >> 4) & 1;
    f32x4 acc0 = {0.f, 0.f, 0.f, 0.f}, acc1 = {0.f, 0.f, 0.f, 0.f};
    f32x4 vac0 = {0.f, 0.f, 0.f, 0.f}, vac1 = {0.f, 0.f, 0.f, 0.f};
    const s16x8* whfrag = (const s16x8*)whp + (size_t)((wpk * 2 + cg) * 16) * 64 + lane;
#pragma unroll
    for (int g = 0; g < 16; g++) {
        s16x8 bf = whfrag[g * 64];
        s16x8 a0 = *(const s16x8*)&sh[col][g * 32 + kq * 8];
        s16x8 a1 = *(const s16x8*)&sh[16 + col][g * 32 + kq * 8];
        acc0 = MFMA16(a0, bf, acc0);
        acc1 = MFMA16(a1, bf, acc1);
    }
    const s16x8* wxfrag = (const s16x8*)wxp + (size_t)((wpk * 2 + cg) * 2) * 64 + lane;
#pragma unroll
    for (int g = 0; g < 2; g++) {
        s16x8 bf = wxfrag[g * 64];
        s16x8 a0 = *(const s16x8*)&sx[col][g * 32 + kq * 8];
        s16x8 a1 = *(const s16x8*)&sx[16 + col][g * 32 + kq * 8];
        acc0 = MFMA16(a0, bf, acc0);
        acc1 = MFMA16(a1, bf, acc1);
        s16x8 d0 = *(const s16x8*)&sxd[col][g * 32 + kq * 8];
        s16x8 d1 = *(const s16x8*)&sxd[16 + col][g * 32 + kq * 8];
        vac0 = MFMA16(d0, bf, vac0);
        vac1 = MFMA16(d1, bf, vac1);
    }
    int ic = isub + col;
    float bias = b0g[ic];
#pragma unroll
    for (int r = 0; r < 4; r++) {
        int bb = b0 + kq * 4 + r;
        float l1a = acc0[r] + bias;
        float dra = 1.f / (1.f + expf(-l1a));
        relu_b[bb * HH + ic] = f2bf(fmaxf(l1a, 0.f));
        drelu_f[bb * HH + ic] = dra;
        s0_b[bb * HH + ic] = f2bf(dra * vac0[r]);
        float l1b = acc1[r] + bias;
        float drb = 1.f / (1.f + expf(-l1b));
        relu_b[(bb + 16) * HH + ic] = f2bf(fmaxf(l1b, 0.f));
        drelu_f[(bb + 16) * HH + ic] = drb;
        s0_b[(bb + 16) * HH + ic] = f2bf(drb * vac1[r]);
    }
}

// ---------------------------------------------------------------------------
// k_th: z = relu@wout^T + b1 -> th=tanh(z), dtanh=1-th^2 (f32)
//       fused: curr0 = dtanh * (s0@wout^T); stores curr0 f32 row-major and
//       bf16 A-frag. Also zeroes the loop kernel's sync flags (block 0,0).
// ---------------------------------------------------------------------------
__global__ void k_th(const unsigned short* __restrict__ wop, const unsigned short* __restrict__ relu_b,
                     const unsigned short* __restrict__ s0_b, const float* __restrict__ b1g,
                     float* __restrict__ dtanh_f, unsigned short* __restrict__ curr_b,
                     float* __restrict__ curr0_f, unsigned int* __restrict__ flg) {
    __shared__ unsigned short sr[32][520];
    __shared__ unsigned short ss0[32][520];
    int tid = threadIdx.x;
    if (blockIdx.x == 0 && blockIdx.y == 0) {  // zero 512 flag words (32 flags, 64B stride)
        flg[tid] = 0u;
        flg[tid + 256] = 0u;
    }
    int b0 = blockIdx.x * 32;
    int it = blockIdx.y;
    for (int idx = tid; idx < 32 * 64; idx += 256) {
        int r = idx >> 6, c8 = idx & 63;
        *(int4*)&sr[r][c8 * 8] = *(const int4*)&relu_b[(b0 + r) * HH + c8 * 8];
        *(int4*)&ss0[r][c8 * 8] = *(const int4*)&s0_b[(b0 + r) * HH + c8 * 8];
    }
    __syncthreads();
    int wv = tid >> 6, lane = tid & 63, col = lane & 15, kq = lane >> 4;
    int isub = it * 64 + wv * 16;
    int wpk = isub >> 5, cg = (isub >> 4) & 1;
    f32x4 acc0 = {0.f, 0.f, 0.f, 0.f}, acc1 = {0.f, 0.f, 0.f, 0.f};
    f32x4 cac0 = {0.f, 0.f, 0.f, 0.f}, cac1 = {0.f, 0.f, 0.f, 0.f};
    const s16x8* wofrag = (const s16x8*)wop + (size_t)((wpk * 2 + cg) * 16) * 64 + lane;
#pragma unroll
    for (int g = 0; g < 16; g++) {
        s16x8 bf = wofrag[g * 64];
        s16x8 a0 = *(const s16x8*)&sr[col][g * 32 + kq * 8];
        s16x8 a1 = *(const s16x8*)&sr[16 + col][g * 32 + kq * 8];
        acc0 = MFMA16(a0, bf, acc0);
        acc1 = MFMA16(a1, bf, acc1);
        s16x8 p0 = *(const s16x8*)&ss0[col][g * 32 + kq * 8];
        s16x8 p1 = *(const s16x8*)&ss0[16 + col][g * 32 + kq * 8];
        cac0 = MFMA16(p0, bf, cac0);
        cac1 = MFMA16(p1, bf, cac1);
    }
    int ic = isub + col;
    float bias = b1g[ic];
    int fc = (ic >> 5) * 512 + (ic & 7) + (((ic >> 3) & 3) << 7);
#pragma unroll
    for (int r = 0; r < 4; r++) {
        int bb = b0 + kq * 4 + r;
        int row8 = (kq * 4 + r) * 8;
        float th_a = tanhf(acc0[r] + bias);
        float dta = 1.f - th_a * th_a;
        float c0a = dta * cac0[r];
        dtanh_f[bb * HH + ic] = dta;
        curr_b[(bb >> 4) * 8192 + fc + row8] = f2bf(c0a);
        curr0_f[bb * HH + ic] = c0a;
        float th_b = tanhf(acc1[r] + bias);
        float dtb = 1.f - th_b * th_b;
        float c0b = dtb * cac1[r];
        dtanh_f[(bb + 16) * HH + ic] = dtb;
        curr_b[((bb + 16) >> 4) * 8192 + fc + row8] = f2bf(c0b);
        curr0_f[(bb + 16) * HH + ic] = c0b;
    }
}

// ---------------------------------------------------------------------------
// k_loop9: k_loop8 skeleton with ONE change: weight prefetch depth 1 -> 8.
// Model (fits rounds 1/5/6/7/8): phase time was 16 sequential g-steps each
// gated by an exposed ~230cy L2 load latency (depth-1 bfr dbuf + per-barrier
// vmcnt(0) drains), NOT bandwidth (halving bytes in r6 saved only 15%), NOT
// wave count (r5 null), NOT exchange mechanics (r6/7/8 all ~61us).
// Fix: per phase, burst-load all 8 own-half B-frag groups into bfr[8][2]
// (fully unrolled, compile-time indices only); during part-1 each consumed
// slot is refilled with the partner-half group (issued 8+ steps + one
// barrier ahead of use -> hidden). One cold latency per phase instead of 16.
// Everything else byte-identical to k_loop8 (proven protocol).
// ---------------------------------------------------------------------------
__global__ __launch_bounds__(512) void k_loop9(
    const unsigned short* __restrict__ whp, const unsigned short* __restrict__ wop,
    const unsigned short* __restrict__ curr_b, const float* __restrict__ curr0_f,
    const float* __restrict__ drelu_f, const float* __restrict__ dtanh_f,
    unsigned short* __restrict__ xch, unsigned int* flg,
    float* __restrict__ outp) {
    __shared__ __align__(16) unsigned short sa[2][8192];  // ping-pong A-frag (16KB each)
    const int tid = threadIdx.x;
    const int w = tid >> 6, lane = tid & 63;
    const int col2 = lane & 15, kq = lane >> 4;
    const int c = blockIdx.x & 15;   // chain (batch tile)
    const int s = blockIdx.x >> 4;   // column half

    // stage curr0 full tile (A-frag from k_th) into sa[0]: 1024 int4
    {
        const int4* src = (const int4*)(curr_b + (size_t)c * 8192);
        int4* dst = (int4*)&sa[0][0];
        dst[tid] = src[tid];
        dst[tid + 512] = src[tid + 512];
    }

    // per-thread diagonals + h_dot accumulator: 2 col-tiles x 4 rows (my half)
    float dr[2][4], dt[2][4], hd[2][4];
#pragma unroll
    for (int t = 0; t < 2; t++) {
        const int cc = s * 256 + (w * 2 + t) * 16 + col2;
#pragma unroll
        for (int r = 0; r < 4; r++) {
            const int row = c * 16 + kq * 4 + r;
            dr[t][r] = drelu_f[row * HH + cc];
            dt[t][r] = dtanh_f[row * HH + cc];
            hd[t][r] = curr0_f[row * HH + cc];
        }
    }

    // LDS halfword index (r=0) within a half for (row m=kq*4+r, local tile ct=w*2+t)
    int fbl[2];
#pragma unroll
    for (int t = 0; t < 2; t++)
        fbl[t] = w * 512 + (col2 & 7) + (((t * 2 + (col2 >> 3)) & 3) << 7) + kq * 32;
    const int myhalf = s * 4096;         // halfword offset of my K-half in an A-frag tile
    const int phalf = (1 - s) * 4096;

    // wave's B-frag base within my col-half: absolute col tiles s*16 + w*2 + t.
    const s16x8* wlh = (const s16x8*)whp + (size_t)(s * 16 + w * 2) * 1024 + lane;
    const s16x8* wlo = (const s16x8*)wop + (size_t)(s * 16 + w * 2) * 1024 + lane;
    const unsigned short* A0 = &sa[0][lane * 8];
    const unsigned short* A1 = &sa[1][lane * 8];
    unsigned int* fme = flg + (s * 16 + c) * 16;         // own 64B line
    unsigned int* fpr = flg + ((1 - s) * 16 + c) * 16;
    const int sK = s << 9;               // s16x8 offset of K-group s*8 in a col-tile
    const int pK = (1 - s) << 9;

    __syncthreads();  // curr0 staged

    for (int p = 0; p < 16; p++) {
        const s16x8* wl = (p & 1) ? wlo : wlh;          // even: wh, odd: wout
        const unsigned short* Ar = (p & 1) ? A1 : A0;   // read sa[p&1]
        const s16x8* w1 = wl + sK;                      // own-half K groups
        const s16x8* w2 = wl + pK;                      // partner-half K groups

        // ---- burst-prefetch ALL 8 own-half B-frag groups (depth-8) ----
        s16x8 bfr[8][2];
#pragma unroll
        for (int d = 0; d < 8; d++) {
#pragma unroll
            for (int t = 0; t < 2; t++) bfr[d][t] = w1[t * 1024 + d * 64];
        }

        // ---- issue-early exchange-in: spin (steady state: immediate), then
        //      load partner's packed half into registers; consume after part 1.
        unsigned long long v0 = 0ull, v1 = 0ull;
        if (p) {
            while (__hip_atomic_load(fpr, __ATOMIC_RELAXED, __HIP_MEMORY_SCOPE_AGENT)
                   < (unsigned)p) { __builtin_amdgcn_s_sleep(1); }
            const unsigned long long* gsrc = (const unsigned long long*)
                (xch + ((size_t)(c * 2 + ((p - 1) & 1)) * 2 + (1 - s)) * 4096);
            v0 = __hip_atomic_load(&gsrc[tid], __ATOMIC_RELAXED, __HIP_MEMORY_SCOPE_AGENT);
            v1 = __hip_atomic_load(&gsrc[tid + 512], __ATOMIC_RELAXED, __HIP_MEMORY_SCOPE_AGENT);
        }

        f32x4 acc[2] = {{0.f, 0.f, 0.f, 0.f}, {0.f, 0.f, 0.f, 0.f}};
        // ---- part 1: own K-half; refill each consumed slot with the
        //      partner-half group (used 8+ steps + one barrier later) ----
#pragma unroll
        for (int j = 0; j < 8; j++) {
            const s16x8 a = *(const s16x8*)(Ar + myhalf + j * 512);
#pragma unroll
            for (int t = 0; t < 2; t++) acc[t] = MFMA16(a, bfr[j][t], acc[t]);
#pragma unroll
            for (int t = 0; t < 2; t++) bfr[j][t] = w2[t * 1024 + j * 64];
        }
        // ---- unpack staged partner half into LDS (loads done during part 1) ----
        if (p) {
            unsigned short* ph = &sa[p & 1][phalf];
#pragma unroll
            for (int r = 0; r < 4; r++) {
                ph[fbl[0] + r * 8] = (unsigned short)(v0 >> (16 * r));
                ph[fbl[1] + r * 8] = (unsigned short)(v1 >> (16 * r));
            }
        }
        __syncthreads();  // partner half visible to all waves
        // ---- part 2: partner K-half (weights already resident in bfr) ----
#pragma unroll
        for (int j = 0; j < 8; j++) {
            const s16x8 a = *(const s16x8*)(Ar + phalf + j * 512);
#pragma unroll
            for (int t = 0; t < 2; t++) acc[t] = MFMA16(a, bfr[j][t], acc[t]);
        }
        // ---- epilogue: LDS own-half write + register-sourced packed export ----
        unsigned short* Aw = &sa[(p + 1) & 1][0];
        if (p < 15) {
            unsigned long long pk0 = 0ull, pk1 = 0ull;
            if (p & 1) {        // wout phase: curr' = dtanh*(s@wout^T); h_dot += curr'
#pragma unroll
                for (int r = 0; r < 4; r++) {
                    float va = dt[0][r] * acc[0][r];
                    hd[0][r] += va;
                    unsigned short ba = f2bf(va);
                    Aw[myhalf + fbl[0] + r * 8] = ba;
                    pk0 |= (unsigned long long)ba << (16 * r);
                    float vb = dt[1][r] * acc[1][r];
                    hd[1][r] += vb;
                    unsigned short bb = f2bf(vb);
                    Aw[myhalf + fbl[1] + r * 8] = bb;
                    pk1 |= (unsigned long long)bb << (16 * r);
                }
            } else {            // wh phase: s = drelu*(curr@wh^T)
#pragma unroll
                for (int r = 0; r < 4; r++) {
                    unsigned short ba = f2bf(dr[0][r] * acc[0][r]);
                    Aw[myhalf + fbl[0] + r * 8] = ba;
                    pk0 |= (unsigned long long)ba << (16 * r);
                    unsigned short bb = f2bf(dr[1][r] * acc[1][r]);
                    Aw[myhalf + fbl[1] + r * 8] = bb;
                    pk1 |= (unsigned long long)bb << (16 * r);
                }
            }
            unsigned long long* gdst = (unsigned long long*)
                (xch + ((size_t)(c * 2 + (p & 1)) * 2 + s) * 4096);
            __hip_atomic_store(&gdst[tid], pk0, __ATOMIC_RELAXED, __HIP_MEMORY_SCOPE_AGENT);
            __hip_atomic_store(&gdst[tid + 512], pk1, __ATOMIC_RELAXED, __HIP_MEMORY_SCOPE_AGENT);
            __syncthreads();    // drains LDS writes AND the export stores (vmcnt(0))
            if (tid == 0)
                __hip_atomic_store(fme, (unsigned)(p + 1), __ATOMIC_RELEASE, __HIP_MEMORY_SCOPE_AGENT);
        } else {                // p == 15 (wout): accumulate only
#pragma unroll
            for (int t = 0; t < 2; t++)
#pragma unroll
                for (int r = 0; r < 4; r++) hd[t][r] += dt[t][r] * acc[t][r];
        }
    }

#pragma unroll
    for (int t = 0; t < 2; t++) {
        const int cc = s * 256 + (w * 2 + t) * 16 + col2;
#pragma unroll
        for (int r = 0; r < 4; r++)
            outp[(size_t)(c * 16 + kq * 4 + r) * HH + cc] = hd[t][r];
    }
}

// ---------------------------------------------------------------------------
extern "C" void kernel_launch(void* const* d_in, const int* in_sizes, int n_in,
                              void* d_out, int out_size, void* d_ws, size_t ws_size,
                              hipStream_t stream) {
    const float* tg = (const float*)d_in[0];
    const float* h = (const float*)d_in[1];
    const float* coeffs = (const float*)d_in[2];
    const float* dcoeffs = (const float*)d_in[3];
    const float* tobs = (const float*)d_in[4];
    const float* wx = (const float*)d_in[5];
    const float* wh = (const float*)d_in[6];
    const float* wout = (const float*)d_in[7];
    const float* b0g = (const float*)d_in[8];
    const float* b1g = (const float*)d_in[9];
    float* outp = (float*)d_out;

    char* ws = (char*)d_ws;
    unsigned short* whp    = (unsigned short*)(ws + 0);        // 512KB packed bf16
    unsigned short* wop    = (unsigned short*)(ws + 524288);   // 512KB
    unsigned short* wxp    = (unsigned short*)(ws + 1048576);  // 64KB
    unsigned short* hb     = (unsigned short*)(ws + 1114112);  // 256KB
    unsigned short* xb     = (unsigned short*)(ws + 1376256);  // 32KB
    unsigned short* xdb    = (unsigned short*)(ws + 1409024);  // 32KB
    unsigned short* relu_b = (unsigned short*)(ws + 1441792);  // 256KB (dead after k_th)
    unsigned short* s0_b   = (unsigned short*)(ws + 1703936);  // 256KB (dead after k_th)
    float* drelu_f         = (float*)(ws + 1966080);           // 512KB
    float* dtanh_f         = (float*)(ws + 2490368);           // 512KB
    unsigned short* curr_b = (unsigned short*)(ws + 3014656);  // 256KB (A-frag)
    float* curr0_f         = (float*)(ws + 3276800);           // 512KB
    unsigned short* xch    = (unsigned short*)(ws + 1441792);  // 512KB exchange (overlays relu/s0)
    unsigned int* flg      = (unsigned int*)(ws + 3801088);    // 2KB flags

    k_pack<<<2752, 256, 0, stream>>>(wh, wout, wx, h, coeffs, dcoeffs, tobs, tg,
                                     whp, wop, wxp, hb, xb, xdb);
    k_l1<<<dim3(8, 8), 256, 0, stream>>>(whp, wxp, hb, xb, xdb, b0g, relu_b, drelu_f, s0_b);
    k_th<<<dim3(8, 8), 256, 0, stream>>>(wop, relu_b, s0_b, b1g, dtanh_f, curr_b, curr0_f, flg);
    k_loop9<<<32, 512, 0, stream>>>(whp, wop, curr_b, curr0_f, drelu_f, dtanh_f, xch, flg, outp);
}

// Round 11
// 161.627 us; speedup vs baseline: 1.0739x; 1.0181x over previous
//
#include <hip/hip_runtime.h>

// Problem constants
#define BB 256   // batch
#define HH 512   // hidden
#define CC 64    // spline channels
#define NN 100   // time knots
#define KT 8     // K_TERMS

typedef short s16x8 __attribute__((ext_vector_type(8)));
typedef float f32x4 __attribute__((ext_vector_type(4)));

#define MFMA16(a, b, c) __builtin_amdgcn_mfma_f32_16x16x32_bf16((a), (b), (c), 0, 0, 0)

static __device__ __forceinline__ unsigned short f2bf(float f) {
    union { float f; unsigned int u; } v; v.f = f;
    unsigned int r = v.u + 0x7FFFu + ((v.u >> 16) & 1u);  // RNE
    return (unsigned short)(r >> 16);
}

// ---------------------------------------------------------------------------
// A-frag layout for a 16-row x 512-col bf16 activation tile t (8192 halfwords):
//   F[t*8192 + g*512 + lane*8 + e] = M[lane&15][g*32 + (lane>>4)*8 + e]
// K-quarter q (cols [q*128,(q+1)*128)) = halfwords [q*2048,(q+1)*2048).
// ---------------------------------------------------------------------------

// ---------------------------------------------------------------------------
// k_pack: weight bf16 conversion into MFMA-frag-packed layout + h conversion +
// cubic spline evaluation (x, xdot).  (Round-1 proven version.)
// ---------------------------------------------------------------------------
__global__ void k_pack(const float* __restrict__ wh, const float* __restrict__ wout,
                       const float* __restrict__ wx, const float* __restrict__ h,
                       const float* __restrict__ coeffs, const float* __restrict__ dcoeffs,
                       const float* __restrict__ tobs, const float* __restrict__ tg,
                       unsigned short* __restrict__ whp, unsigned short* __restrict__ wop,
                       unsigned short* __restrict__ wxp, unsigned short* __restrict__ hb,
                       unsigned short* __restrict__ xb, unsigned short* __restrict__ xdb) {
    int gid = blockIdx.x * 256 + threadIdx.x;
    if (gid < 524288) {                       // wh / wout packed (262144 each)
        const float* src = (gid < 262144) ? wh : wout;
        unsigned short* dst = (gid < 262144) ? whp : wop;
        int p = gid & 262143;
        int e = p & 7, lane = (p >> 3) & 63, g = (p >> 9) & 15, cg = (p >> 13) & 1, w = p >> 14;
        int row = w * 32 + cg * 16 + (lane & 15);
        int k = g * 32 + (lane >> 4) * 8 + e;
        dst[p] = f2bf(src[row * HH + k]);
    } else if (gid < 557056) {                // wx packed (32768)
        int p = gid - 524288;
        int e = p & 7, lane = (p >> 3) & 63, g = (p >> 9) & 1, cg = (p >> 10) & 1, w = p >> 11;
        int row = w * 32 + cg * 16 + (lane & 15);
        int k = g * 32 + (lane >> 4) * 8 + e;
        wxp[p] = f2bf(wx[row * CC + k]);
    } else if (gid < 688128) {                // h -> bf16 row-major (131072)
        int p = gid - 557056;
        hb[p] = f2bf(h[p]);
    } else if (gid < 704512) {                // spline eval: x, xdot (16384)
        int p = gid - 688128;
        int b = p >> 6, c = p & 63;
        float t = tg[0];
        int cntv = 0;
        for (int n = 0; n < NN; n++) cntv += (tobs[n] <= t) ? 1 : 0;
        int idx = cntv - 1;
        idx = idx < 0 ? 0 : (idx > NN - 2 ? NN - 2 : idx);  // clip to [0, 98]
        float dt = t - tobs[idx];
        const float* cb = coeffs + ((size_t)(b * (NN - 1) + idx) * 4) * CC + c;
        float xv = cb[0] + dt * (cb[CC] + dt * (cb[2 * CC] + dt * cb[3 * CC]));
        const float* db = dcoeffs + ((size_t)(b * (NN - 1) + idx) * 4) * CC + c;
        float xd = db[0] + dt * (db[CC] + dt * (db[2 * CC] + dt * db[3 * CC]));
        xb[p] = f2bf(xv);
        xdb[p] = f2bf(xd);
    }
}

// ---------------------------------------------------------------------------
// k_l1: l1 = x@wx^T + h@wh^T + b0 -> relu(bf16), drelu=sigmoid(l1) (f32)
//       fused: v = xdot@wx^T ; s0 = drelu*v (bf16)          (round-1 proven)
// ---------------------------------------------------------------------------
__global__ void k_l1(const unsigned short* __restrict__ whp, const unsigned short* __restrict__ wxp,
                     const unsigned short* __restrict__ hb, const unsigned short* __restrict__ xb,
                     const unsigned short* __restrict__ xdb, const float* __restrict__ b0g,
                     unsigned short* __restrict__ relu_b, float* __restrict__ drelu_f,
                     unsigned short* __restrict__ s0_b) {
    __shared__ unsigned short sh[32][520];
    __shared__ unsigned short sx[32][72];
    __shared__ unsigned short sxd[32][72];
    int tid = threadIdx.x;
    int b0 = blockIdx.x * 32;
    int it = blockIdx.y;
    for (int idx = tid; idx < 32 * 64; idx += 256) {
        int r = idx >> 6, c8 = idx & 63;
        *(int4*)&sh[r][c8 * 8] = *(const int4*)&hb[(b0 + r) * HH + c8 * 8];
    }
    for (int idx = tid; idx < 32 * 8; idx += 256) {
        int r = idx >> 3, c8 = idx & 7;
        *(int4*)&sx[r][c8 * 8] = *(const int4*)&xb[(b0 + r) * CC + c8 * 8];
        *(int4*)&sxd[r][c8 * 8] = *(const int4*)&xdb[(b0 + r) * CC + c8 * 8];
    }
    __syncthreads();
    int wv = tid >> 6, lane = tid & 63, col = lane & 15, kq = lane >> 4;
    int isub = it * 64 + wv * 16;
    int wpk = isub >> 5, cg = (isub >> 4) & 1;
    f32x4 acc0 = {0.f, 0.f, 0.f, 0.f}, acc1 = {0.f, 0.f, 0.f, 0.f};
    f32x4 vac0 = {0.f, 0.f, 0.f, 0.f}, vac1 = {0.f, 0.f, 0.f, 0.f};
    const s16x8* whfrag = (const s16x8*)whp + (size_t)((wpk * 2 + cg) * 16) * 64 + lane;
#pragma unroll
    for (int g = 0; g < 16; g++) {
        s16x8 bf = whfrag[g * 64];
        s16x8 a0 = *(const s16x8*)&sh[col][g * 32 + kq * 8];
        s16x8 a1 = *(const s16x8*)&sh[16 + col][g * 32 + kq * 8];
        acc0 = MFMA16(a0, bf, acc0);
        acc1 = MFMA16(a1, bf, acc1);
    }
    const s16x8* wxfrag = (const s16x8*)wxp + (size_t)((wpk * 2 + cg) * 2) * 64 + lane;
#pragma unroll
    for (int g = 0; g < 2; g++) {
        s16x8 bf = wxfrag[g * 64];
        s16x8 a0 = *(const s16x8*)&sx[col][g * 32 + kq * 8];
        s16x8 a1 = *(const s16x8*)&sx[16 + col][g * 32 + kq * 8];
        acc0 = MFMA16(a0, bf, acc0);
        acc1 = MFMA16(a1, bf, acc1);
        s16x8 d0 = *(const s16x8*)&sxd[col][g * 32 + kq * 8];
        s16x8 d1 = *(const s16x8*)&sxd[16 + col][g * 32 + kq * 8];
        vac0 = MFMA16(d0, bf, vac0);
        vac1 = MFMA16(d1, bf, vac1);
    }
    int ic = isub + col;
    float bias = b0g[ic];
#pragma unroll
    for (int r = 0; r < 4; r++) {
        int bb = b0 + kq * 4 + r;
        float l1a = acc0[r] + bias;
        float dra = 1.f / (1.f + expf(-l1a));
        relu_b[bb * HH + ic] = f2bf(fmaxf(l1a, 0.f));
        drelu_f[bb * HH + ic] = dra;
        s0_b[bb * HH + ic] = f2bf(dra * vac0[r]);
        float l1b = acc1[r] + bias;
        float drb = 1.f / (1.f + expf(-l1b));
        relu_b[(bb + 16) * HH + ic] = f2bf(fmaxf(l1b, 0.f));
        drelu_f[(bb + 16) * HH + ic] = drb;
        s0_b[(bb + 16) * HH + ic] = f2bf(drb * vac1[r]);
    }
}

// ---------------------------------------------------------------------------
// k_th: z = relu@wout^T + b1 -> th=tanh(z), dtanh=1-th^2 (f32)
//       fused: curr0 = dtanh * (s0@wout^T); stores curr0 f32 row-major and
//       bf16 A-frag. Also zeroes the loop kernel's 64 sync flags (block 0,0).
// ---------------------------------------------------------------------------
__global__ void k_th(const unsigned short* __restrict__ wop, const unsigned short* __restrict__ relu_b,
                     const unsigned short* __restrict__ s0_b, const float* __restrict__ b1g,
                     float* __restrict__ dtanh_f, unsigned short* __restrict__ curr_b,
                     float* __restrict__ curr0_f, unsigned int* __restrict__ flg) {
    __shared__ unsigned short sr[32][520];
    __shared__ unsigned short ss0[32][520];
    int tid = threadIdx.x;
    if (blockIdx.x == 0 && blockIdx.y == 0) {  // zero 1024 flag words (64 flags, 64B stride)
        flg[tid] = 0u;
        flg[tid + 256] = 0u;
        flg[tid + 512] = 0u;
        flg[tid + 768] = 0u;
    }
    int b0 = blockIdx.x * 32;
    int it = blockIdx.y;
    for (int idx = tid; idx < 32 * 64; idx += 256) {
        int r = idx >> 6, c8 = idx & 63;
        *(int4*)&sr[r][c8 * 8] = *(const int4*)&relu_b[(b0 + r) * HH + c8 * 8];
        *(int4*)&ss0[r][c8 * 8] = *(const int4*)&s0_b[(b0 + r) * HH + c8 * 8];
    }
    __syncthreads();
    int wv = tid >> 6, lane = tid & 63, col = lane & 15, kq = lane >> 4;
    int isub = it * 64 + wv * 16;
    int wpk = isub >> 5, cg = (isub >> 4) & 1;
    f32x4 acc0 = {0.f, 0.f, 0.f, 0.f}, acc1 = {0.f, 0.f, 0.f, 0.f};
    f32x4 cac0 = {0.f, 0.f, 0.f, 0.f}, cac1 = {0.f, 0.f, 0.f, 0.f};
    const s16x8* wofrag = (const s16x8*)wop + (size_t)((wpk * 2 + cg) * 16) * 64 + lane;
#pragma unroll
    for (int g = 0; g < 16; g++) {
        s16x8 bf = wofrag[g * 64];
        s16x8 a0 = *(const s16x8*)&sr[col][g * 32 + kq * 8];
        s16x8 a1 = *(const s16x8*)&sr[16 + col][g * 32 + kq * 8];
        acc0 = MFMA16(a0, bf, acc0);
        acc1 = MFMA16(a1, bf, acc1);
        s16x8 p0 = *(const s16x8*)&ss0[col][g * 32 + kq * 8];
        s16x8 p1 = *(const s16x8*)&ss0[16 + col][g * 32 + kq * 8];
        cac0 = MFMA16(p0, bf, cac0);
        cac1 = MFMA16(p1, bf, cac1);
    }
    int ic = isub + col;
    float bias = b1g[ic];
    int fc = (ic >> 5) * 512 + (ic & 7) + (((ic >> 3) & 3) << 7);
#pragma unroll
    for (int r = 0; r < 4; r++) {
        int bb = b0 + kq * 4 + r;
        int row8 = (kq * 4 + r) * 8;
        float th_a = tanhf(acc0[r] + bias);
        float dta = 1.f - th_a * th_a;
        float c0a = dta * cac0[r];
        dtanh_f[bb * HH + ic] = dta;
        curr_b[(bb >> 4) * 8192 + fc + row8] = f2bf(c0a);
        curr0_f[bb * HH + ic] = c0a;
        float th_b = tanhf(acc1[r] + bias);
        float dtb = 1.f - th_b * th_b;
        float c0b = dtb * cac1[r];
        dtanh_f[(bb + 16) * HH + ic] = dtb;
        curr_b[((bb + 16) >> 4) * 8192 + fc + row8] = f2bf(c0b);
        curr0_f[(bb + 16) * HH + ic] = c0b;
    }
}

// ---------------------------------------------------------------------------
// k_loop10: 4-way split Neumann loop. 64 blocks x 512 threads: block =
// (q<<4)|c handles chain c, column quarter q (128 cols, 8 tiles, 1/wave).
// Per phase each block streams only ITS 128KB weight slice; exports 4KB
// (1 u64/thread, register-packed) and imports 3x4KB from its 3 partners.
// All r8/r9 machinery retained: thread-major slots, issue-early imports
// hidden under part-1, burst prefetch of ALL 16 weight groups (64 VGPR,
// one tile/wave), 2 barriers/phase, relaxed sc1 spin + RELEASE flag.
// Runtime-q register indexing avoided (rule #20): weight groups are loaded
// in ROTATED order so own-quarter groups are always bfr[0..3] (compile-time
// indices; rotation is address arithmetic); partner arrays use unrolled
// j!=q guards. K accumulation order is a per-block rotation (fp32 reorder).
// Flag/slot race proof as r6-8, extended to 3 partners: my overwrite of slot
// parity (p&1) at phase p+2 follows my spin on all partner flags >= p+2,
// which follows their phase-p+1 imports of my phase-p data.
// (Round-10 resubmission: fb_own_kbase helper inlined — was a use-before-
// declaration compile error; no functional change.)
// ---------------------------------------------------------------------------
__global__ __launch_bounds__(512) void k_loop10(
    const unsigned short* __restrict__ whp, const unsigned short* __restrict__ wop,
    const unsigned short* __restrict__ curr_b, const float* __restrict__ curr0_f,
    const float* __restrict__ drelu_f, const float* __restrict__ dtanh_f,
    unsigned short* __restrict__ xch, unsigned int* flg,
    float* __restrict__ outp) {
    __shared__ __align__(16) unsigned short sa[2][8192];  // ping-pong A-frag (16KB each)
    const int tid = threadIdx.x;
    const int w = tid >> 6, lane = tid & 63;
    const int col2 = lane & 15, kq = lane >> 4;
    const int c = blockIdx.x & 15;   // chain (batch tile)
    const int q = blockIdx.x >> 4;   // column quarter (0..3)

    // stage curr0 full tile (A-frag from k_th) into sa[0]: 1024 int4
    {
        const int4* src = (const int4*)(curr_b + (size_t)c * 8192);
        int4* dst = (int4*)&sa[0][0];
        dst[tid] = src[tid];
        dst[tid + 512] = src[tid + 512];
    }

    // per-thread diagonals + h_dot accumulator: 1 col-tile x 4 rows (my quarter)
    const int cc = (q * 8 + w) * 16 + col2;     // my output column
    float dr[4], dt[4], hd[4];
#pragma unroll
    for (int r = 0; r < 4; r++) {
        const int row = c * 16 + kq * 4 + r;
        dr[r] = drelu_f[row * HH + cc];
        dt[r] = dtanh_f[row * HH + cc];
        hd[r] = curr0_f[row * HH + cc];
    }

    // A-frag halfword index (r=0) for col k=(j*8+w)*16+col2 of quarter j:
    //   fblq[j] = (j*4 + (w>>1))*512 + (col2&7) + (((w*2+(col2>>3))&3)<<7) + kq*32
    const int fcom = (w >> 1) * 512 + (col2 & 7) + (((w * 2 + (col2 >> 3)) & 3) << 7) + kq * 32;
    int fblq[4];
#pragma unroll
    for (int j = 0; j < 4; j++) fblq[j] = j * 2048 + fcom;
    const int fb_own = q * 2048 + fcom;         // == fblq[q], computed without runtime index

    // wave's B-frag base: my col tile is q*8+w; frag (tile,g) at ((tile*16+g)*64+lane)
    const s16x8* wlh = (const s16x8*)whp + (size_t)(q * 8 + w) * 1024 + lane;
    const s16x8* wlo = (const s16x8*)wop + (size_t)(q * 8 + w) * 1024 + lane;
    const unsigned short* A0 = &sa[0][lane * 8];
    const unsigned short* A1 = &sa[1][lane * 8];
    unsigned int* fme = flg + (q * 16 + c) * 16;          // own 64B line

    __syncthreads();  // curr0 staged

    for (int p = 0; p < 16; p++) {
        const s16x8* wl = (p & 1) ? wlo : wlh;            // even: wh, odd: wout
        const unsigned short* Ar = (p & 1) ? A1 : A0;     // read sa[p&1]

        // ---- burst-prefetch ALL 16 weight groups, ROTATED so own quarter's
        //      groups (g = q*4..q*4+3) land in bfr[0..3] (compile-time idx) ----
        s16x8 bfr[16];
#pragma unroll
        for (int d = 0; d < 16; d++) bfr[d] = wl[(((q << 2) + d) & 15) * 64];

        // ---- issue-early imports: spin on 3 partner flags, load 3 u64 ----
        unsigned long long v[4] = {0ull, 0ull, 0ull, 0ull};
        if (p) {
#pragma unroll
            for (int j = 0; j < 4; j++) {
                if (j != q) {
                    const unsigned int* fj = flg + (j * 16 + c) * 16;
                    while (__hip_atomic_load(fj, __ATOMIC_RELAXED, __HIP_MEMORY_SCOPE_AGENT)
                           < (unsigned)p) { __builtin_amdgcn_s_sleep(1); }
                }
            }
#pragma unroll
            for (int j = 0; j < 4; j++) {
                if (j != q) {
                    const unsigned long long* gsrc = (const unsigned long long*)(void*)xch
                        + ((size_t)(c * 2 + ((p - 1) & 1)) * 4 + j) * 512;
                    v[j] = __hip_atomic_load(&gsrc[tid], __ATOMIC_RELAXED, __HIP_MEMORY_SCOPE_AGENT);
                }
            }
        }

        f32x4 acc = {0.f, 0.f, 0.f, 0.f};
        // ---- part 1: own K-quarter (groups q*4+j at halfword q*2048 + j*512;
        //      data in LDS from my previous epilogue) ----
#pragma unroll
        for (int j = 0; j < 4; j++) {
            const s16x8 a = *(const s16x8*)(Ar + q * 2048 + j * 512);
            acc = MFMA16(a, bfr[j], acc);
        }
        // ---- unpack imported partner quarters into LDS ----
        if (p) {
            unsigned short* ph = &sa[p & 1][0];
#pragma unroll
            for (int j = 0; j < 4; j++) {
                if (j != q) {
#pragma unroll
                    for (int r = 0; r < 4; r++)
                        ph[fblq[j] + r * 8] = (unsigned short)(v[j] >> (16 * r));
                }
            }
        }
        __syncthreads();  // all quarters of sa[p&1] visible
        // ---- part 2: remaining 12 K-groups (rotated order; weights resident) ----
#pragma unroll
        for (int j = 4; j < 16; j++) {
            const int go = (((q << 2) + j) & 15) * 512;   // runtime-uniform LDS offset
            const s16x8 a = *(const s16x8*)(Ar + go);
            acc = MFMA16(a, bfr[j], acc);
        }
        // ---- epilogue: LDS own-quarter write + register-packed export ----
        unsigned short* Aw = &sa[(p + 1) & 1][0];
        if (p < 15) {
            unsigned long long pk = 0ull;
            if (p & 1) {        // wout phase: curr' = dtanh*(s@wout^T); h_dot += curr'
#pragma unroll
                for (int r = 0; r < 4; r++) {
                    const float vv = dt[r] * acc[r];
                    hd[r] += vv;
                    const unsigned short b = f2bf(vv);
                    Aw[fb_own + r * 8] = b;
                    pk |= (unsigned long long)b << (16 * r);
                }
            } else {            // wh phase: s = drelu*(curr@wh^T)
#pragma unroll
                for (int r = 0; r < 4; r++) {
                    const unsigned short b = f2bf(dr[r] * acc[r]);
                    Aw[fb_own + r * 8] = b;
                    pk |= (unsigned long long)b << (16 * r);
                }
            }
            unsigned long long* gdst = (unsigned long long*)(void*)xch
                + ((size_t)(c * 2 + (p & 1)) * 4 + q) * 512;
            __hip_atomic_store(&gdst[tid], pk, __ATOMIC_RELAXED, __HIP_MEMORY_SCOPE_AGENT);
            __syncthreads();    // drains LDS writes AND the export store (vmcnt(0))
            if (tid == 0)
                __hip_atomic_store(fme, (unsigned)(p + 1), __ATOMIC_RELEASE, __HIP_MEMORY_SCOPE_AGENT);
        } else {                // p == 15 (wout): accumulate only
#pragma unroll
            for (int r = 0; r < 4; r++) hd[r] += dt[r] * acc[r];
        }
    }

#pragma unroll
    for (int r = 0; r < 4; r++)
        outp[(size_t)(c * 16 + kq * 4 + r) * HH + cc] = hd[r];
}

// ---------------------------------------------------------------------------
extern "C" void kernel_launch(void* const* d_in, const int* in_sizes, int n_in,
                              void* d_out, int out_size, void* d_ws, size_t ws_size,
                              hipStream_t stream) {
    const float* tg = (const float*)d_in[0];
    const float* h = (const float*)d_in[1];
    const float* coeffs = (const float*)d_in[2];
    const float* dcoeffs = (const float*)d_in[3];
    const float* tobs = (const float*)d_in[4];
    const float* wx = (const float*)d_in[5];
    const float* wh = (const float*)d_in[6];
    const float* wout = (const float*)d_in[7];
    const float* b0g = (const float*)d_in[8];
    const float* b1g = (const float*)d_in[9];
    float* outp = (float*)d_out;

    char* ws = (char*)d_ws;
    unsigned short* whp    = (unsigned short*)(ws + 0);        // 512KB packed bf16
    unsigned short* wop    = (unsigned short*)(ws + 524288);   // 512KB
    unsigned short* wxp    = (unsigned short*)(ws + 1048576);  // 64KB
    unsigned short* hb     = (unsigned short*)(ws + 1114112);  // 256KB
    unsigned short* xb     = (unsigned short*)(ws + 1376256);  // 32KB
    unsigned short* xdb    = (unsigned short*)(ws + 1409024);  // 32KB
    unsigned short* relu_b = (unsigned short*)(ws + 1441792);  // 256KB (dead after k_th)
    unsigned short* s0_b   = (unsigned short*)(ws + 1703936);  // 256KB (dead after k_th)
    float* drelu_f         = (float*)(ws + 1966080);           // 512KB
    float* dtanh_f         = (float*)(ws + 2490368);           // 512KB
    unsigned short* curr_b = (unsigned short*)(ws + 3014656);  // 256KB (A-frag)
    float* curr0_f         = (float*)(ws + 3276800);           // 512KB
    unsigned short* xch    = (unsigned short*)(ws + 1441792);  // 512KB exchange (overlays relu/s0)
    unsigned int* flg      = (unsigned int*)(ws + 3801088);    // 4KB flags (64 x 64B)

    k_pack<<<2752, 256, 0, stream>>>(wh, wout, wx, h, coeffs, dcoeffs, tobs, tg,
                                     whp, wop, wxp, hb, xb, xdb);
    k_l1<<<dim3(8, 8), 256, 0, stream>>>(whp, wxp, hb, xb, xdb, b0g, relu_b, drelu_f, s0_b);
    k_th<<<dim3(8, 8), 256, 0, stream>>>(wop, relu_b, s0_b, b1g, dtanh_f, curr_b, curr0_f, flg);
    k_loop10<<<64, 512, 0, stream>>>(whp, wop, curr_b, curr0_f, drelu_f, dtanh_f, xch, flg, outp);
}

// Round 12
// 155.972 us; speedup vs baseline: 1.1128x; 1.0363x over previous
//
#include <hip/hip_runtime.h>

// Problem constants
#define BB 256   // batch
#define HH 512   // hidden
#define CC 64    // spline channels
#define NN 100   // time knots
#define KT 8     // K_TERMS

typedef short s16x8 __attribute__((ext_vector_type(8)));
typedef float f32x4 __attribute__((ext_vector_type(4)));

#define MFMA16(a, b, c) __builtin_amdgcn_mfma_f32_16x16x32_bf16((a), (b), (c), 0, 0, 0)

static __device__ __forceinline__ unsigned short f2bf(float f) {
    union { float f; unsigned int u; } v; v.f = f;
    unsigned int r = v.u + 0x7FFFu + ((v.u >> 16) & 1u);  // RNE
    return (unsigned short)(r >> 16);
}

// ---------------------------------------------------------------------------
// A-frag layout for a 16-row x 512-col bf16 activation tile t (8192 halfwords):
//   F[t*8192 + g*512 + lane*8 + e] = M[lane&15][g*32 + (lane>>4)*8 + e]
// K-quarter q (cols [q*128,(q+1)*128)) = halfwords [q*2048,(q+1)*2048).
// ---------------------------------------------------------------------------

// ---------------------------------------------------------------------------
// k_pack: weight bf16 conversion into MFMA-frag-packed layout + h conversion +
// cubic spline evaluation (x, xdot).  (Round-1 proven version.)
// ---------------------------------------------------------------------------
__global__ void k_pack(const float* __restrict__ wh, const float* __restrict__ wout,
                       const float* __restrict__ wx, const float* __restrict__ h,
                       const float* __restrict__ coeffs, const float* __restrict__ dcoeffs,
                       const float* __restrict__ tobs, const float* __restrict__ tg,
                       unsigned short* __restrict__ whp, unsigned short* __restrict__ wop,
                       unsigned short* __restrict__ wxp, unsigned short* __restrict__ hb,
                       unsigned short* __restrict__ xb, unsigned short* __restrict__ xdb) {
    int gid = blockIdx.x * 256 + threadIdx.x;
    if (gid < 524288) {                       // wh / wout packed (262144 each)
        const float* src = (gid < 262144) ? wh : wout;
        unsigned short* dst = (gid < 262144) ? whp : wop;
        int p = gid & 262143;
        int e = p & 7, lane = (p >> 3) & 63, g = (p >> 9) & 15, cg = (p >> 13) & 1, w = p >> 14;
        int row = w * 32 + cg * 16 + (lane & 15);
        int k = g * 32 + (lane >> 4) * 8 + e;
        dst[p] = f2bf(src[row * HH + k]);
    } else if (gid < 557056) {                // wx packed (32768)
        int p = gid - 524288;
        int e = p & 7, lane = (p >> 3) & 63, g = (p >> 9) & 1, cg = (p >> 10) & 1, w = p >> 11;
        int row = w * 32 + cg * 16 + (lane & 15);
        int k = g * 32 + (lane >> 4) * 8 + e;
        wxp[p] = f2bf(wx[row * CC + k]);
    } else if (gid < 688128) {                // h -> bf16 row-major (131072)
        int p = gid - 557056;
        hb[p] = f2bf(h[p]);
    } else if (gid < 704512) {                // spline eval: x, xdot (16384)
        int p = gid - 688128;
        int b = p >> 6, c = p & 63;
        float t = tg[0];
        int cntv = 0;
        for (int n = 0; n < NN; n++) cntv += (tobs[n] <= t) ? 1 : 0;
        int idx = cntv - 1;
        idx = idx < 0 ? 0 : (idx > NN - 2 ? NN - 2 : idx);  // clip to [0, 98]
        float dt = t - tobs[idx];
        const float* cb = coeffs + ((size_t)(b * (NN - 1) + idx) * 4) * CC + c;
        float xv = cb[0] + dt * (cb[CC] + dt * (cb[2 * CC] + dt * cb[3 * CC]));
        const float* db = dcoeffs + ((size_t)(b * (NN - 1) + idx) * 4) * CC + c;
        float xd = db[0] + dt * (db[CC] + dt * (db[2 * CC] + dt * db[3 * CC]));
        xb[p] = f2bf(xv);
        xdb[p] = f2bf(xd);
    }
}

// ---------------------------------------------------------------------------
// k_l1: l1 = x@wx^T + h@wh^T + b0 -> relu(bf16), drelu=sigmoid(l1) (f32)
//       fused: v = xdot@wx^T ; s0 = drelu*v (bf16)          (round-1 proven)
// ---------------------------------------------------------------------------
__global__ void k_l1(const unsigned short* __restrict__ whp, const unsigned short* __restrict__ wxp,
                     const unsigned short* __restrict__ hb, const unsigned short* __restrict__ xb,
                     const unsigned short* __restrict__ xdb, const float* __restrict__ b0g,
                     unsigned short* __restrict__ relu_b, float* __restrict__ drelu_f,
                     unsigned short* __restrict__ s0_b) {
    __shared__ unsigned short sh[32][520];
    __shared__ unsigned short sx[32][72];
    __shared__ unsigned short sxd[32][72];
    int tid = threadIdx.x;
    int b0 = blockIdx.x * 32;
    int it = blockIdx.y;
    for (int idx = tid; idx < 32 * 64; idx += 256) {
        int r = idx >> 6, c8 = idx & 63;
        *(int4*)&sh[r][c8 * 8] = *(const int4*)&hb[(b0 + r) * HH + c8 * 8];
    }
    for (int idx = tid; idx < 32 * 8; idx += 256) {
        int r = idx >> 3, c8 = idx & 7;
        *(int4*)&sx[r][c8 * 8] = *(const int4*)&xb[(b0 + r) * CC + c8 * 8];
        *(int4*)&sxd[r][c8 * 8] = *(const int4*)&xdb[(b0 + r) * CC + c8 * 8];
    }
    __syncthreads();
    int wv = tid >> 6, lane = tid & 63, col = lane & 15, kq = lane >> 4;
    int isub = it * 64 + wv * 16;
    int wpk = isub >> 5, cg = (isub >> 4) & 1;
    f32x4 acc0 = {0.f, 0.f, 0.f, 0.f}, acc1 = {0.f, 0.f, 0.f, 0.f};
    f32x4 vac0 = {0.f, 0.f, 0.f, 0.f}, vac1 = {0.f, 0.f, 0.f, 0.f};
    const s16x8* whfrag = (const s16x8*)whp + (size_t)((wpk * 2 + cg) * 16) * 64 + lane;
#pragma unroll
    for (int g = 0; g < 16; g++) {
        s16x8 bf = whfrag[g * 64];
        s16x8 a0 = *(const s16x8*)&sh[col][g * 32 + kq * 8];
        s16x8 a1 = *(const s16x8*)&sh[16 + col][g * 32 + kq * 8];
        acc0 = MFMA16(a0, bf, acc0);
        acc1 = MFMA16(a1, bf, acc1);
    }
    const s16x8* wxfrag = (const s16x8*)wxp + (size_t)((wpk * 2 + cg) * 2) * 64 + lane;
#pragma unroll
    for (int g = 0; g < 2; g++) {
        s16x8 bf = wxfrag[g * 64];
        s16x8 a0 = *(const s16x8*)&sx[col][g * 32 + kq * 8];
        s16x8 a1 = *(const s16x8*)&sx[16 + col][g * 32 + kq * 8];
        acc0 = MFMA16(a0, bf, acc0);
        acc1 = MFMA16(a1, bf, acc1);
        s16x8 d0 = *(const s16x8*)&sxd[col][g * 32 + kq * 8];
        s16x8 d1 = *(const s16x8*)&sxd[16 + col][g * 32 + kq * 8];
        vac0 = MFMA16(d0, bf, vac0);
        vac1 = MFMA16(d1, bf, vac1);
    }
    int ic = isub + col;
    float bias = b0g[ic];
#pragma unroll
    for (int r = 0; r < 4; r++) {
        int bb = b0 + kq * 4 + r;
        float l1a = acc0[r] + bias;
        float dra = 1.f / (1.f + expf(-l1a));
        relu_b[bb * HH + ic] = f2bf(fmaxf(l1a, 0.f));
        drelu_f[bb * HH + ic] = dra;
        s0_b[bb * HH + ic] = f2bf(dra * vac0[r]);
        float l1b = acc1[r] + bias;
        float drb = 1.f / (1.f + expf(-l1b));
        relu_b[(bb + 16) * HH + ic] = f2bf(fmaxf(l1b, 0.f));
        drelu_f[(bb + 16) * HH + ic] = drb;
        s0_b[(bb + 16) * HH + ic] = f2bf(drb * vac1[r]);
    }
}

// ---------------------------------------------------------------------------
// k_th: z = relu@wout^T + b1 -> th=tanh(z), dtanh=1-th^2 (f32)
//       fused: curr0 = dtanh * (s0@wout^T); stores curr0 f32 row-major and
//       bf16 A-frag. Also zeroes the loop kernel's 64 sync flags (block 0,0).
// ---------------------------------------------------------------------------
__global__ void k_th(const unsigned short* __restrict__ wop, const unsigned short* __restrict__ relu_b,
                     const unsigned short* __restrict__ s0_b, const float* __restrict__ b1g,
                     float* __restrict__ dtanh_f, unsigned short* __restrict__ curr_b,
                     float* __restrict__ curr0_f, unsigned int* __restrict__ flg) {
    __shared__ unsigned short sr[32][520];
    __shared__ unsigned short ss0[32][520];
    int tid = threadIdx.x;
    if (blockIdx.x == 0 && blockIdx.y == 0) {  // zero 1024 flag words (64 flags, 64B stride)
        flg[tid] = 0u;
        flg[tid + 256] = 0u;
        flg[tid + 512] = 0u;
        flg[tid + 768] = 0u;
    }
    int b0 = blockIdx.x * 32;
    int it = blockIdx.y;
    for (int idx = tid; idx < 32 * 64; idx += 256) {
        int r = idx >> 6, c8 = idx & 63;
        *(int4*)&sr[r][c8 * 8] = *(const int4*)&relu_b[(b0 + r) * HH + c8 * 8];
        *(int4*)&ss0[r][c8 * 8] = *(const int4*)&s0_b[(b0 + r) * HH + c8 * 8];
    }
    __syncthreads();
    int wv = tid >> 6, lane = tid & 63, col = lane & 15, kq = lane >> 4;
    int isub = it * 64 + wv * 16;
    int wpk = isub >> 5, cg = (isub >> 4) & 1;
    f32x4 acc0 = {0.f, 0.f, 0.f, 0.f}, acc1 = {0.f, 0.f, 0.f, 0.f};
    f32x4 cac0 = {0.f, 0.f, 0.f, 0.f}, cac1 = {0.f, 0.f, 0.f, 0.f};
    const s16x8* wofrag = (const s16x8*)wop + (size_t)((wpk * 2 + cg) * 16) * 64 + lane;
#pragma unroll
    for (int g = 0; g < 16; g++) {
        s16x8 bf = wofrag[g * 64];
        s16x8 a0 = *(const s16x8*)&sr[col][g * 32 + kq * 8];
        s16x8 a1 = *(const s16x8*)&sr[16 + col][g * 32 + kq * 8];
        acc0 = MFMA16(a0, bf, acc0);
        acc1 = MFMA16(a1, bf, acc1);
        s16x8 p0 = *(const s16x8*)&ss0[col][g * 32 + kq * 8];
        s16x8 p1 = *(const s16x8*)&ss0[16 + col][g * 32 + kq * 8];
        cac0 = MFMA16(p0, bf, cac0);
        cac1 = MFMA16(p1, bf, cac1);
    }
    int ic = isub + col;
    float bias = b1g[ic];
    int fc = (ic >> 5) * 512 + (ic & 7) + (((ic >> 3) & 3) << 7);
#pragma unroll
    for (int r = 0; r < 4; r++) {
        int bb = b0 + kq * 4 + r;
        int row8 = (kq * 4 + r) * 8;
        float th_a = tanhf(acc0[r] + bias);
        float dta = 1.f - th_a * th_a;
        float c0a = dta * cac0[r];
        dtanh_f[bb * HH + ic] = dta;
        curr_b[(bb >> 4) * 8192 + fc + row8] = f2bf(c0a);
        curr0_f[bb * HH + ic] = c0a;
        float th_b = tanhf(acc1[r] + bias);
        float dtb = 1.f - th_b * th_b;
        float c0b = dtb * cac1[r];
        dtanh_f[(bb + 16) * HH + ic] = dtb;
        curr_b[((bb + 16) >> 4) * 8192 + fc + row8] = f2bf(c0b);
        curr0_f[(bb + 16) * HH + ic] = c0b;
    }
}

// ---------------------------------------------------------------------------
// k_loop11: 4-way split Neumann loop with WEIGHTS FULLY PINNED IN REGISTERS.
// Change vs k_loop10 (49.6us): each wave owns ONE col-tile; its complete
// wh+wout weight slice is 32 frags = 128 VGPRs, loaded ONCE before the loop
// (rotated order, as r11, so all in-loop register indices are compile-time
// constants — rule #20). Zero per-phase weight traffic (was 128KB/phase
// redundant L2 re-fetch, ~1.1us of the 3.1us phase). The wh/wout choice is a
// block-uniform if(p&1) around a macro body (NO ternary-selected pointer to
// a register array, which would force scratch). Live state ~180 VGPR < 256
// allowed by __launch_bounds__(512,2) (r3's spill was ~284 live).
// Exchange protocol byte-identical to k_loop10 (proven r6-r11).
// ---------------------------------------------------------------------------
#define PHASE_COMPUTE(BW) do {                                                 \
    /* part 1: own K-quarter (groups q*4+j at halfword q*2048 + j*512) */      \
    _Pragma("unroll")                                                          \
    for (int j = 0; j < 4; j++) {                                              \
        const s16x8 a = *(const s16x8*)(Ar + q * 2048 + j * 512);              \
        acc = MFMA16(a, (BW)[j], acc);                                         \
    }                                                                          \
    /* unpack imported partner quarters into LDS */                            \
    if (p) {                                                                   \
        unsigned short* ph = &sa[p & 1][0];                                    \
        _Pragma("unroll")                                                      \
        for (int j = 0; j < 4; j++) {                                          \
            if (j != q) {                                                      \
                _Pragma("unroll")                                              \
                for (int r = 0; r < 4; r++)                                    \
                    ph[fblq[j] + r * 8] = (unsigned short)(v[j] >> (16 * r));  \
            }                                                                  \
        }                                                                      \
    }                                                                          \
    __syncthreads();  /* all quarters of sa[p&1] visible */                    \
    /* part 2: remaining 12 K-groups (rotated order) */                        \
    _Pragma("unroll")                                                          \
    for (int j = 4; j < 16; j++) {                                             \
        const int go = (((q << 2) + j) & 15) * 512;                            \
        const s16x8 a = *(const s16x8*)(Ar + go);                              \
        acc = MFMA16(a, (BW)[j], acc);                                         \
    }                                                                          \
} while (0)

__global__ __launch_bounds__(512, 2) void k_loop11(
    const unsigned short* __restrict__ whp, const unsigned short* __restrict__ wop,
    const unsigned short* __restrict__ curr_b, const float* __restrict__ curr0_f,
    const float* __restrict__ drelu_f, const float* __restrict__ dtanh_f,
    unsigned short* __restrict__ xch, unsigned int* flg,
    float* __restrict__ outp) {
    __shared__ __align__(16) unsigned short sa[2][8192];  // ping-pong A-frag (16KB each)
    const int tid = threadIdx.x;
    const int w = tid >> 6, lane = tid & 63;
    const int col2 = lane & 15, kq = lane >> 4;
    const int c = blockIdx.x & 15;   // chain (batch tile)
    const int q = blockIdx.x >> 4;   // column quarter (0..3)

    // stage curr0 full tile (A-frag from k_th) into sa[0]: 1024 int4
    {
        const int4* src = (const int4*)(curr_b + (size_t)c * 8192);
        int4* dst = (int4*)&sa[0][0];
        dst[tid] = src[tid];
        dst[tid + 512] = src[tid + 512];
    }

    // per-thread diagonals + h_dot accumulator: 1 col-tile x 4 rows (my quarter)
    const int cc = (q * 8 + w) * 16 + col2;     // my output column
    float dr[4], dt[4], hd[4];
#pragma unroll
    for (int r = 0; r < 4; r++) {
        const int row = c * 16 + kq * 4 + r;
        dr[r] = drelu_f[row * HH + cc];
        dt[r] = dtanh_f[row * HH + cc];
        hd[r] = curr0_f[row * HH + cc];
    }

    // A-frag halfword index (r=0) for col k=(j*8+w)*16+col2 of quarter j
    const int fcom = (w >> 1) * 512 + (col2 & 7) + (((w * 2 + (col2 >> 3)) & 3) << 7) + kq * 32;
    int fblq[4];
#pragma unroll
    for (int j = 0; j < 4; j++) fblq[j] = j * 2048 + fcom;
    const int fb_own = q * 2048 + fcom;         // == fblq[q], no runtime index

    // ---- one-time: pin my col-tile's FULL weight slice in registers ----
    // rotated order: bwh[d] = wh frag (tile q*8+w, K-group (q*4+d)&15)
    const s16x8* wlh = (const s16x8*)whp + (size_t)(q * 8 + w) * 1024 + lane;
    const s16x8* wlo = (const s16x8*)wop + (size_t)(q * 8 + w) * 1024 + lane;
    s16x8 bwh[16], bwo[16];
#pragma unroll
    for (int d = 0; d < 16; d++) {
        const int gg = (((q << 2) + d) & 15) * 64;
        bwh[d] = wlh[gg];
        bwo[d] = wlo[gg];
    }

    const unsigned short* A0 = &sa[0][lane * 8];
    const unsigned short* A1 = &sa[1][lane * 8];
    unsigned int* fme = flg + (q * 16 + c) * 16;          // own 64B line

    __syncthreads();  // curr0 staged

    for (int p = 0; p < 16; p++) {
        const unsigned short* Ar = (p & 1) ? A1 : A0;     // read sa[p&1]

        // ---- issue-early imports: spin on 3 partner flags, load 3 u64 ----
        unsigned long long v[4] = {0ull, 0ull, 0ull, 0ull};
        if (p) {
#pragma unroll
            for (int j = 0; j < 4; j++) {
                if (j != q) {
                    const unsigned int* fj = flg + (j * 16 + c) * 16;
                    while (__hip_atomic_load(fj, __ATOMIC_RELAXED, __HIP_MEMORY_SCOPE_AGENT)
                           < (unsigned)p) { __builtin_amdgcn_s_sleep(1); }
                }
            }
#pragma unroll
            for (int j = 0; j < 4; j++) {
                if (j != q) {
                    const unsigned long long* gsrc = (const unsigned long long*)(void*)xch
                        + ((size_t)(c * 2 + ((p - 1) & 1)) * 4 + j) * 512;
                    v[j] = __hip_atomic_load(&gsrc[tid], __ATOMIC_RELAXED, __HIP_MEMORY_SCOPE_AGENT);
                }
            }
        }

        f32x4 acc = {0.f, 0.f, 0.f, 0.f};
        if (p & 1) {            // wout phase (block-uniform branch)
            PHASE_COMPUTE(bwo);
        } else {                // wh phase
            PHASE_COMPUTE(bwh);
        }

        // ---- epilogue: LDS own-quarter write + register-packed export ----
        unsigned short* Aw = &sa[(p + 1) & 1][0];
        if (p < 15) {
            unsigned long long pk = 0ull;
            if (p & 1) {        // wout phase: curr' = dtanh*(s@wout^T); h_dot += curr'
#pragma unroll
                for (int r = 0; r < 4; r++) {
                    const float vv = dt[r] * acc[r];
                    hd[r] += vv;
                    const unsigned short b = f2bf(vv);
                    Aw[fb_own + r * 8] = b;
                    pk |= (unsigned long long)b << (16 * r);
                }
            } else {            // wh phase: s = drelu*(curr@wh^T)
#pragma unroll
                for (int r = 0; r < 4; r++) {
                    const unsigned short b = f2bf(dr[r] * acc[r]);
                    Aw[fb_own + r * 8] = b;
                    pk |= (unsigned long long)b << (16 * r);
                }
            }
            unsigned long long* gdst = (unsigned long long*)(void*)xch
                + ((size_t)(c * 2 + (p & 1)) * 4 + q) * 512;
            __hip_atomic_store(&gdst[tid], pk, __ATOMIC_RELAXED, __HIP_MEMORY_SCOPE_AGENT);
            __syncthreads();    // drains LDS writes AND the export store (vmcnt(0))
            if (tid == 0)
                __hip_atomic_store(fme, (unsigned)(p + 1), __ATOMIC_RELEASE, __HIP_MEMORY_SCOPE_AGENT);
        } else {                // p == 15 (wout): accumulate only
#pragma unroll
            for (int r = 0; r < 4; r++) hd[r] += dt[r] * acc[r];
        }
    }

#pragma unroll
    for (int r = 0; r < 4; r++)
        outp[(size_t)(c * 16 + kq * 4 + r) * HH + cc] = hd[r];
}

// ---------------------------------------------------------------------------
extern "C" void kernel_launch(void* const* d_in, const int* in_sizes, int n_in,
                              void* d_out, int out_size, void* d_ws, size_t ws_size,
                              hipStream_t stream) {
    const float* tg = (const float*)d_in[0];
    const float* h = (const float*)d_in[1];
    const float* coeffs = (const float*)d_in[2];
    const float* dcoeffs = (const float*)d_in[3];
    const float* tobs = (const float*)d_in[4];
    const float* wx = (const float*)d_in[5];
    const float* wh = (const float*)d_in[6];
    const float* wout = (const float*)d_in[7];
    const float* b0g = (const float*)d_in[8];
    const float* b1g = (const float*)d_in[9];
    float* outp = (float*)d_out;

    char* ws = (char*)d_ws;
    unsigned short* whp    = (unsigned short*)(ws + 0);        // 512KB packed bf16
    unsigned short* wop    = (unsigned short*)(ws + 524288);   // 512KB
    unsigned short* wxp    = (unsigned short*)(ws + 1048576);  // 64KB
    unsigned short* hb     = (unsigned short*)(ws + 1114112);  // 256KB
    unsigned short* xb     = (unsigned short*)(ws + 1376256);  // 32KB
    unsigned short* xdb    = (unsigned short*)(ws + 1409024);  // 32KB
    unsigned short* relu_b = (unsigned short*)(ws + 1441792);  // 256KB (dead after k_th)
    unsigned short* s0_b   = (unsigned short*)(ws + 1703936);  // 256KB (dead after k_th)
    float* drelu_f         = (float*)(ws + 1966080);           // 512KB
    float* dtanh_f         = (float*)(ws + 2490368);           // 512KB
    unsigned short* curr_b = (unsigned short*)(ws + 3014656);  // 256KB (A-frag)
    float* curr0_f         = (float*)(ws + 3276800);           // 512KB
    unsigned short* xch    = (unsigned short*)(ws + 1441792);  // 512KB exchange (overlays relu/s0)
    unsigned int* flg      = (unsigned int*)(ws + 3801088);    // 4KB flags (64 x 64B)

    k_pack<<<2752, 256, 0, stream>>>(wh, wout, wx, h, coeffs, dcoeffs, tobs, tg,
                                     whp, wop, wxp, hb, xb, xdb);
    k_l1<<<dim3(8, 8), 256, 0, stream>>>(whp, wxp, hb, xb, xdb, b0g, relu_b, drelu_f, s0_b);
    k_th<<<dim3(8, 8), 256, 0, stream>>>(wop, relu_b, s0_b, b1g, dtanh_f, curr_b, curr0_f, flg);
    k_loop11<<<64, 512, 0, stream>>>(whp, wop, curr_b, curr0_f, drelu_f, dtanh_f, xch, flg, outp);
}